// Round 15
// baseline (515.212 us; speedup 1.0000x reference)
//
#include <hip/hip_runtime.h>
#include <hip/hip_bf16.h>

// MambaSpatial: B=32, C_IN=D=96, H=W=48, L=2304, K=2, N=16, R=6.
// R4-R13: segmented scan (32-step, NSEG=72), native-transcendental scan math,
// packed v2f, xv[32] reg prefetch, O(L^2) rank argsort, channel-split x4
// inproj/final, fused gather2, parallel LN stats. R13 = 499.2us.
// R14 FAILED: de-LDS'd scans. R15: B-half staging, neutral.
// R16/R17 FAILED: (192,4) launch_bounds capped VGPR at 128 -> scratch spill
//     (scan3ln then scan1). R18 (502us): both at (192,3), no spill,
//     LN conflict-free map kept (SQ_LDS_BANK_CONFLICT 1769K -> 0).
// R19: flat profile -> harvest mid-tier kernels (all bit-identical math):
//     (a) k_xdbl output-split 22/16 in ONE 2304-block launch (9 -> 18
//         waves/CU; duplicate xstd reads L2/L3-absorbed, same as inproj);
//     (b) k_conv_silu 4 outputs/thread (grid 27648 -> 6912, same ki,kj
//         accumulation order per element);
//     (c) k_bnfin fused into k_final (drop the 1-block serialization
//         bubble; sc/sh computed inline per d, identical formula).
// conv_silu/sim math deliberately UNCHANGED (feeds argsort; near-tie order).

typedef __hip_bfloat16 bf16;
typedef float v2f __attribute__((ext_vector_type(2)));
typedef float v4f __attribute__((ext_vector_type(4)));
#define SH2(V, a, b) __builtin_shufflevector(V, V, a, b)

__device__ __forceinline__ float b2f(bf16 v) { return __bfloat162float(v); }
__device__ __forceinline__ float ldu(const void* p, int i, bool f32) {
  if (f32) return ((const float*)p)[i];
  return b2f(((const bf16*)p)[i]);
}
__device__ __forceinline__ float rcp_f(float x) { return __builtin_amdgcn_rcpf(x); }

#define LL 2304
#define NSEG 72          // 32-step segments

// ---- wbuf offsets (floats) ----
#define W_INT  0        // in_proj_w transposed [c][d] 9216
#define B_IN   9216
#define W_C2D  9312
#define B_C2D  10176
#define W_LOC  10272
#define B_LOC  11136
#define BN_G   11232
#define BN_B   11328
#define W_XPT  11424    // x_proj_w transposed [d][80]
#define W_DT   19104    // dt_projs_w [k][d][6]
#define B_DT   20256
#define A2OF   20448    // -exp(A_logs)*log2(e) [k][d][16]
#define DSOF   23520
#define LN_G   23712
#define LN_B   23808
#define W_OUTT 23904    // out_proj_w transposed [d][c]
#define B_OUT  33120
#define WBUF_N 33280ul

// ---- workspace layout (float offsets) ----
#define O_WBUF  0ul
#define O_XFEAT 33280ul        // 7,077,888 ; reused: hend ; then ymdm
#define O_XCONV 7111168ul      // 7,077,888
#define O_SIM   14189056ul
#define O_SIDX  14262784ul
#define O_XST   14336512ul     // sorted l-major [b][l][d] ; reused: lcbuf
#define O_XSTD  21414400ul     // sorted d-major [b][d][l] ; reused: hstart
#define O_RBUF  28492288ul     // [b][k][l][8]
#define O_BC    29671936ul     // [b][k][l][32]
#define O_DSUM  34390528ul     // [b][k][d][72] 442,368
#define O_YMLM  34832896ul     // [b][p][96] 7,077,888
#define O_STATS 41910784ul
#define O_AFLG  41910976ul
#define O_SCSH  41911040ul
#define O_FLAG  41911232ul
#define O_END   41911296ul     // ~167.6 MB

// ---------------- dtype detect ----------------
__global__ void k_detect(const void* x, float* flag) {
  int i = threadIdx.x;
  bool bad = false;
  const bf16* xb = (const bf16*)x;
#pragma unroll
  for (int r = 0; r < 4; ++r) {
    float v = b2f(xb[r * 64 + i]);
    if (!(fabsf(v) <= 1e4f)) bad = true;
  }
  bool any = __any(bad);
  if (i == 0) flag[0] = any ? 1.f : 0.f;
}

// ---------------- prep ----------------
__global__ void k_prep(const void* ipw, const void* ipb, const void* c2w, const void* c2b,
                       const void* lw, const void* lb, const void* bng, const void* bnb,
                       const void* xpw, const void* dtw, const void* dtb, const void* alog,
                       const void* dss, const void* ng, const void* nb, const void* opw,
                       const void* opb, float* wb, const float* flag, float* aflag) {
  bool f = flag[0] > 0.5f;
  int i = blockIdx.x * 256 + threadIdx.x;
  if (i < 9216) {
    int r = i / 96, c = i % 96;
    wb[W_INT + c * 96 + r] = ldu(ipw, i, f);
    wb[W_OUTT + c * 96 + r] = ldu(opw, i, f);
  }
  if (i < 96) {
    wb[B_IN + i] = ldu(ipb, i, f); wb[B_C2D + i] = ldu(c2b, i, f); wb[B_LOC + i] = ldu(lb, i, f);
    wb[BN_G + i] = ldu(bng, i, f); wb[BN_B + i] = ldu(bnb, i, f); wb[LN_G + i] = ldu(ng, i, f);
    wb[LN_B + i] = ldu(nb, i, f); wb[B_OUT + i] = ldu(opb, i, f);
  }
  if (i < 864) { wb[W_C2D + i] = ldu(c2w, i, f); wb[W_LOC + i] = ldu(lw, i, f); }
  if (i < 7296) {
    int k = i / 3648, c = (i / 96) % 38, d = i % 96;
    wb[W_XPT + d * 80 + k * 38 + c] = ldu(xpw, i, f);
  }
  if (i < 1152) wb[W_DT + i] = ldu(dtw, i, f);
  if (i < 192) { wb[B_DT + i] = ldu(dtb, i, f); wb[DSOF + i] = ldu(dss, i, f); }
  if (i < 3072) {
    float av = expf(ldu(alog, i, f));
    wb[A2OF + i] = -av * 1.4426950408889634f;
    int n = i % 16;
    if (fabsf(av - (float)(n + 1)) > 1e-3f * (n + 1)) atomicAdd(aflag, 1.f);
  }
}

// ---------------- in_proj (acc-major, d-quarter x4, 128 thr) ----------------
__global__ __launch_bounds__(128, 4)
void k_inproj(const void* __restrict__ x, const float* __restrict__ wb,
              float* __restrict__ xfeat, const float* __restrict__ flag) {
  int b = blockIdx.x / 72;
  int rest = blockIdx.x % 72;
  int q = rest / 18;
  int l = (rest % 18) * 128 + threadIdx.x;
  float acc[24];
#pragma unroll
  for (int j = 0; j < 24; ++j) acc[j] = wb[B_IN + q * 24 + j];
  bool f = flag[0] > 0.5f;
  if (f) {
    const float* xf = (const float*)x;
#pragma unroll 2
    for (int c = 0; c < 96; ++c) {
      float xc = xf[(b * 96 + c) * LL + l];
      const float* wr = wb + W_INT + c * 96 + q * 24;
#pragma unroll
      for (int j = 0; j < 24; ++j) acc[j] += xc * wr[j];
    }
  } else {
    const bf16* xb = (const bf16*)x;
#pragma unroll 2
    for (int c = 0; c < 96; ++c) {
      float xc = b2f(xb[(b * 96 + c) * LL + l]);
      const float* wr = wb + W_INT + c * 96 + q * 24;
#pragma unroll
      for (int j = 0; j < 24; ++j) acc[j] += xc * wr[j];
    }
  }
#pragma unroll
  for (int j = 0; j < 24; ++j) xfeat[(b * 96 + q * 24 + j) * LL + l] = acc[j];
}

// ---------------- depthwise 3x3 + bias + silu (4 outputs/thread) ----------------
__global__ __launch_bounds__(256, 8)
void k_conv_silu(const float* __restrict__ xfeat, const float* __restrict__ wb,
                 float* __restrict__ xconv) {
  int t = blockIdx.x * 256 + threadIdx.x;     // [0, 32*96*576)
  int lq = t % 576; int d = (t / 576) % 96; int b = t / (576 * 96);
  int l0 = lq * 4;
  int h = l0 / 48, w0 = l0 % 48;              // 48%4==0: all 4 outputs same row
  const float* wr = wb + W_C2D + d * 9;
  const float* src = xfeat + (b * 96 + d) * LL;
  float bias = wb[B_C2D + d];
  float acc[4] = {bias, bias, bias, bias};
#pragma unroll
  for (int ki = 0; ki < 3; ++ki) {
    int hh = h + ki - 1; if (hh < 0 || hh >= 48) continue;
    const float* row = src + hh * 48;
#pragma unroll
    for (int kj = 0; kj < 3; ++kj) {
      float wv = wr[ki * 3 + kj];
#pragma unroll
      for (int u = 0; u < 4; ++u) {
        int ww = w0 + u + kj - 1;
        if (ww < 0 || ww >= 48) continue;
        acc[u] += row[ww] * wv;
      }
    }
  }
  float4 o;
  o.x = acc[0] / (1.f + expf(-acc[0]));
  o.y = acc[1] / (1.f + expf(-acc[1]));
  o.z = acc[2] / (1.f + expf(-acc[2]));
  o.w = acc[3] / (1.f + expf(-acc[3]));
  *(float4*)(xconv + (size_t)(b * 96 + d) * LL + l0) = o;
}

// ---------------- cosine-sim vs center pixel ----------------
__global__ __launch_bounds__(256, 8)
void k_sim(const float* __restrict__ xconv, float* __restrict__ sim) {
  int b = blockIdx.x / 9;
  int l = (blockIdx.x % 9) * 256 + threadIdx.x;
  const float* base = xconv + (size_t)b * 96 * LL;
  float dot = 0, nrm = 0, cn = 0;
  for (int d = 0; d < 96; ++d) {
    float v = base[d * LL + l];
    float c = base[d * LL + 1176];
    dot += v * c; nrm += v * v; cn += c * c;
  }
  float den = fmaxf(sqrtf(nrm), 1e-12f) * fmaxf(sqrtf(cn), 1e-12f);
  sim[b * LL + l] = dot / den;
}

// ---------------- stable argsort desc via O(L^2) rank-by-count ----------------
__global__ __launch_bounds__(256, 8)
void k_rank(const float* __restrict__ sim, int* __restrict__ sidx) {
  __shared__ unsigned su[LL];
  int b = blockIdx.x / 36;
  int part = blockIdx.x % 36;
  const float* sp = sim + b * LL;
  for (int i = threadIdx.x; i < LL; i += 256) {
    unsigned u = __float_as_uint(sp[i]);
    u = (u >> 31) ? ~u : (u | 0x80000000u);
    su[i] = u;
  }
  __syncthreads();
  int lq = threadIdx.x >> 2;           // 0..63: element within part
  int ch = threadIdx.x & 3;            // 0..3: j-chunk
  int l = part * 64 + lq;
  unsigned ui = su[l];
  int rank = 0;
  const uint4* s4 = (const uint4*)su;
#pragma unroll 4
  for (int it = 0; it < 144; ++it) {
    int m = 4 * it + ch;
    uint4 U = s4[m];
    int j = 4 * m;
    rank += (int)(U.x > ui) + (int)((U.x == ui) & (j + 0 < l));
    rank += (int)(U.y > ui) + (int)((U.y == ui) & (j + 1 < l));
    rank += (int)(U.z > ui) + (int)((U.z == ui) & (j + 2 < l));
    rank += (int)(U.w > ui) + (int)((U.w == ui) & (j + 3 < l));
  }
  rank += __shfl_xor(rank, 1);
  rank += __shfl_xor(rank, 2);
  if (ch == 0) sidx[b * LL + rank] = l;
}

// ---------------- fused gather + transpose: xconv -> xstd (d-major) + xst (l-major) ----------------
__global__ __launch_bounds__(256, 4)
void k_gather2(const float* __restrict__ xconv, const int* __restrict__ sidx,
               float* __restrict__ xstd, float* __restrict__ xst) {
  __shared__ float tile[64 * 97];
  __shared__ int sp[64];
  int b = blockIdx.x / 36;
  int l0 = (blockIdx.x % 36) * 64;
  if (threadIdx.x < 64) sp[threadIdx.x] = sidx[b * LL + l0 + threadIdx.x];
  __syncthreads();
  const float* base = xconv + (size_t)b * 96 * LL;
#pragma unroll
  for (int it = 0; it < 24; ++it) {
    int idx = it * 256 + threadIdx.x;
    int d = idx / 64, j = idx % 64;
    tile[j * 97 + d] = base[d * LL + sp[j]];
  }
  __syncthreads();
#pragma unroll
  for (int it = 0; it < 24; ++it) {
    int idx = it * 256 + threadIdx.x;
    int r = idx / 96, c = idx % 96;
    xst[((size_t)b * LL + l0 + r) * 96 + c] = tile[r * 97 + c];
  }
#pragma unroll
  for (int it = 0; it < 24; ++it) {
    int idx = it * 256 + threadIdx.x;
    int d = idx / 64, j = idx % 64;
    xstd[((size_t)b * 96 + d) * LL + l0 + j] = tile[j * 97 + d];
  }
}

// ---------------- transpose l-major -> d-major (ymlm -> ymdm) ----------------
__global__ __launch_bounds__(256, 4)
void k_tr_ld(const float* __restrict__ in, float* __restrict__ out) {
  __shared__ float tile[64 * 97];
  int b = blockIdx.x / 36;
  int l0 = (blockIdx.x % 36) * 64;
#pragma unroll
  for (int it = 0; it < 24; ++it) {
    int idx = it * 256 + threadIdx.x;
    int r = idx / 96, c = idx % 96;
    tile[r * 97 + c] = in[((size_t)b * LL + l0 + r) * 96 + c];
  }
  __syncthreads();
#pragma unroll
  for (int it = 0; it < 24; ++it) {
    int idx = it * 256 + threadIdx.x;
    int d = idx / 64, j = idx % 64;
    out[((size_t)b * 96 + d) * LL + l0 + j] = tile[j * 97 + d];
  }
}

// ---------------- x_dbl, output-split 22/16, one 2304-block launch ----------------
__global__ __launch_bounds__(128, 4)
void k_xdbl(const float* __restrict__ xstd, const float* __restrict__ wb,
            float* __restrict__ rbuf, float* __restrict__ bc) {
  int half = blockIdx.x / 1152;
  int r2 = blockIdx.x % 1152;
  int kq = r2 / 576;
  int r = r2 % 576;
  int b = r / 18;
  int l = (r % 18) * 128 + threadIdx.x;
  int lout = kq ? (LL - 1 - l) : l;
  if (half == 0) {
    float acc[22];
#pragma unroll
    for (int j = 0; j < 22; ++j) acc[j] = 0.f;
#pragma unroll 2
    for (int c = 0; c < 96; ++c) {
      float xc = xstd[((size_t)b * 96 + c) * LL + l];
      const float* wr = wb + W_XPT + c * 80 + kq * 38;   // uniform -> s_load
#pragma unroll
      for (int j = 0; j < 22; ++j) acc[j] += xc * wr[j];
    }
    float4* r4 = (float4*)(rbuf + ((size_t)(b * 2 + kq) * LL + lout) * 8);
    r4[0] = make_float4(acc[0], acc[1], acc[2], acc[3]);
    r4[1] = make_float4(acc[4], acc[5], 0.f, 0.f);
    float4* b4 = (float4*)(bc + ((size_t)(b * 2 + kq) * LL + lout) * 32);
#pragma unroll
    for (int i = 0; i < 4; ++i)
      b4[i] = make_float4(acc[6 + 4 * i], acc[7 + 4 * i], acc[8 + 4 * i], acc[9 + 4 * i]);
  } else {
    float acc[16];
#pragma unroll
    for (int j = 0; j < 16; ++j) acc[j] = 0.f;
#pragma unroll 2
    for (int c = 0; c < 96; ++c) {
      float xc = xstd[((size_t)b * 96 + c) * LL + l];
      const float* wr = wb + W_XPT + c * 80 + kq * 38 + 22;
#pragma unroll
      for (int j = 0; j < 16; ++j) acc[j] += xc * wr[j];
    }
    float4* b4 = (float4*)(bc + ((size_t)(b * 2 + kq) * LL + lout) * 32);
#pragma unroll
    for (int i = 0; i < 4; ++i)
      b4[4 + i] = make_float4(acc[4 * i], acc[4 * i + 1], acc[4 * i + 2], acc[4 * i + 3]);
  }
}

// ---------------- scan pass 1: 32-step segments, LDS-staged B-half + rr ----------------
__global__ __launch_bounds__(192, 3)
void k_scan1(const float* __restrict__ rbuf, const float* __restrict__ bc,
             const float* __restrict__ xst, const float* __restrict__ wb,
             float* __restrict__ dsum, float* __restrict__ hend,
             const float* __restrict__ aflag) {
  __shared__ float sbc[2][512];
  __shared__ float srr[2][256];
  int sub = threadIdx.x / 96;
  int tid = threadIdx.x - sub * 96;
  int unit = blockIdx.x * 2 + sub;             // b*144 + k*72 + s
  int s = unit % 72; int k = (unit / 72) % 2; int b = unit / 144;
  int lbase = (b * 2 + k) * LL + s * 32;
  long long lk0 = k ? (LL - 1 - s * 32) : (s * 32);
  long long stp = k ? -96 : 96;
  const float* xp = xst + (size_t)b * LL * 96 + lk0 * 96 + tid;
  float xv[32];
#pragma unroll
  for (int t = 0; t < 32; ++t) xv[t] = xp[t * stp];
  {
    const float4* bsrc = (const float4*)(bc + (size_t)lbase * 32);
    float4* bdst = (float4*)sbc[sub];
    for (int i = tid; i < 128; i += 96) {
      int l = i >> 2, c = i & 3;
      bdst[i] = bsrc[l * 8 + c];     // B-half: first 4 of 8 chunks per l
    }
    const float4* rsrc = (const float4*)(rbuf + (size_t)lbase * 8);
    float4* rdst = (float4*)srr[sub];
    if (tid < 64) rdst[tid] = rsrc[tid];
  }
  __syncthreads();
  int d = tid;
  float wd[6];
#pragma unroll
  for (int j = 0; j < 6; ++j) wd[j] = wb[W_DT + (k * 96 + d) * 6 + j];
  float bd = wb[B_DT + k * 96 + d];
  float ds = 0.f;
  v2f h2[8];
#pragma unroll
  for (int j = 0; j < 8; ++j) h2[j] = (v2f){0.f, 0.f};
  bool fast = (aflag[0] == 0.f);
  if (fast) {
    const v4f* bq4 = (const v4f*)sbc[sub];
    const v4f* rq4 = (const v4f*)srr[sub];
#pragma unroll
    for (int t = 0; t < 32; ++t) {
      v4f r0 = rq4[t * 2], r1 = rq4[t * 2 + 1];
      float a = bd + r0.x * wd[0] + r0.y * wd[1] + r0.z * wd[2]
                   + r0.w * wd[3] + r1.x * wd[4] + r1.y * wd[5];
      float ea = __expf(a);
      float p1 = rcp_f(1.f + ea);
      float dtv = (a > 20.f) ? a : -0.69314718055994531f * __log2f(p1);
      ds += dtv;
      float dtx = dtv * xv[t];
      v2f dt2 = {dtx, dtx};
      float p2s = p1 * p1;
      v2f P1 = {p1, p2s};
      v2f P2 = P1 * (v2f){p2s, p2s};        // p3,p4
      float p4s = P2.y;
      v2f P3 = P1 * (v2f){p4s, p4s};        // p5,p6
      v2f P4 = P2 * (v2f){p4s, p4s};        // p7,p8
      float p8s = P4.y;
      v2f P5 = P1 * (v2f){p8s, p8s};        // p9,p10
      v2f P6 = P2 * (v2f){p8s, p8s};        // p11,p12
      v2f P7 = P3 * (v2f){p8s, p8s};        // p13,p14
      v2f P8 = P4 * (v2f){p8s, p8s};        // p15,p16
      v4f B0 = bq4[t * 4 + 0], B1 = bq4[t * 4 + 1];
      v4f B2 = bq4[t * 4 + 2], B3 = bq4[t * 4 + 3];
      h2[0] = P1 * h2[0] + dt2 * SH2(B0, 0, 1);
      h2[1] = P2 * h2[1] + dt2 * SH2(B0, 2, 3);
      h2[2] = P3 * h2[2] + dt2 * SH2(B1, 0, 1);
      h2[3] = P4 * h2[3] + dt2 * SH2(B1, 2, 3);
      h2[4] = P5 * h2[4] + dt2 * SH2(B2, 0, 1);
      h2[5] = P6 * h2[5] + dt2 * SH2(B2, 2, 3);
      h2[6] = P7 * h2[6] + dt2 * SH2(B3, 0, 1);
      h2[7] = P8 * h2[7] + dt2 * SH2(B3, 2, 3);
    }
  } else {
    float a2[16], hh[16];
#pragma unroll
    for (int n = 0; n < 16; ++n) { a2[n] = wb[A2OF + (k * 96 + d) * 16 + n]; hh[n] = 0.f; }
#pragma unroll 4
    for (int t = 0; t < 32; ++t) {
      const float* rr = &srr[sub][t * 8];
      float a = bd + rr[0] * wd[0] + rr[1] * wd[1] + rr[2] * wd[2]
                   + rr[3] * wd[3] + rr[4] * wd[4] + rr[5] * wd[5];
      float dtv = (a > 20.f) ? a : log1pf(expf(a));
      ds += dtv;
      float dtx = dtv * xv[t];
      const float* bcl = &sbc[sub][t * 16];
#pragma unroll
      for (int n = 0; n < 16; ++n) hh[n] = exp2f(dtv * a2[n]) * hh[n] + dtx * bcl[n];
    }
#pragma unroll
    for (int j = 0; j < 8; ++j) h2[j] = (v2f){hh[2 * j], hh[2 * j + 1]};
  }
  dsum[((b * 2 + k) * 96 + d) * NSEG + s] = ds;
  float4* ho = (float4*)(hend + (((size_t)(b * 2 + k) * NSEG + s) * 96 + d) * 16);
  ho[0] = make_float4(h2[0].x, h2[0].y, h2[1].x, h2[1].y);
  ho[1] = make_float4(h2[2].x, h2[2].y, h2[3].x, h2[3].y);
  ho[2] = make_float4(h2[4].x, h2[4].y, h2[5].x, h2[5].y);
  ho[3] = make_float4(h2[6].x, h2[6].y, h2[7].x, h2[7].y);
}

// ---------------- scan pass 2: stitch 72 segments ----------------
__global__ __launch_bounds__(256, 4)
void k_scan2(const float* __restrict__ dsum, const float* __restrict__ hend,
             const float* __restrict__ wb, float* __restrict__ hstart) {
  int t = blockIdx.x * 256 + threadIdx.x;
  int n = t % 16; int d = (t / 16) % 96; int k = (t / 1536) % 2; int b = t / 3072;
  float a2 = wb[A2OF + (k * 96 + d) * 16 + n];
  float h = 0.f;
  int rowd = ((b * 2 + k) * 96 + d) * NSEG;
#pragma unroll 8
  for (int s = 0; s < NSEG; ++s) {
    size_t idx = (((size_t)(b * 2 + k) * NSEG + s) * 96 + d) * 16 + n;
    hstart[idx] = h;
    h = exp2f(a2 * dsum[rowd + s]) * h + hend[idx];
  }
}

// ---------------- scan3 + combine + LN (32-row tiles, staged) ----------------
__global__ __launch_bounds__(192, 3)
void k_scan3ln(const float* __restrict__ rbuf, const float* __restrict__ bc,
               const float* __restrict__ xst, const float* __restrict__ wb,
               const float* __restrict__ hstart, const int* __restrict__ sidx,
               float* __restrict__ ymlm, const float* __restrict__ aflag) {
  __shared__ float yA[32 * 97];
  __shared__ float yB[32 * 97];
  __shared__ float sbc[2][1024];
  __shared__ float srr[2][256];
  __shared__ float smu[32], srs[32];
  int b = blockIdx.x / NSEG;
  int u = blockIdx.x % NSEG;
  int t = threadIdx.x;
  int sub = t / 96;                      // sub==k
  int d = t - sub * 96;
  int k = sub;
  int seg = sub ? (NSEG - 1 - u) : u;
  int lbase = (b * 2 + k) * LL + seg * 32;
  long long lk0 = k ? (LL - 1 - seg * 32) : (seg * 32);
  long long stp = k ? -96 : 96;
  const float* xp = xst + (size_t)b * LL * 96 + lk0 * 96 + d;
  float xv[32];
#pragma unroll
  for (int i = 0; i < 32; ++i) xv[i] = xp[i * stp];
  {
    const float4* bsrc = (const float4*)(bc + (size_t)lbase * 32);
    float4* bdst = (float4*)sbc[sub];
    for (int i = d; i < 256; i += 96) bdst[i] = bsrc[i];
    const float4* rsrc = (const float4*)(rbuf + (size_t)lbase * 8);
    float4* rdst = (float4*)srr[sub];
    if (d < 64) rdst[d] = rsrc[d];
  }
  __syncthreads();
  {
    float* yacc = sub ? yB : yA;
    float wd[6];
#pragma unroll
    for (int j = 0; j < 6; ++j) wd[j] = wb[W_DT + (k * 96 + d) * 6 + j];
    float bd = wb[B_DT + k * 96 + d];
    float Dv = wb[DSOF + k * 96 + d];
    const float* hi = hstart + (((size_t)(b * 2 + k) * NSEG + seg) * 96 + d) * 16;
    bool fast = (aflag[0] == 0.f);
    if (fast) {
      const v4f* hi4 = (const v4f*)hi;
      v4f H0 = hi4[0], H1 = hi4[1], H2 = hi4[2], H3 = hi4[3];
      v2f h2[8];
      h2[0] = SH2(H0, 0, 1); h2[1] = SH2(H0, 2, 3);
      h2[2] = SH2(H1, 0, 1); h2[3] = SH2(H1, 2, 3);
      h2[4] = SH2(H2, 0, 1); h2[5] = SH2(H2, 2, 3);
      h2[6] = SH2(H3, 0, 1); h2[7] = SH2(H3, 2, 3);
      const v4f* bq4 = (const v4f*)sbc[sub];
      const v4f* rq4 = (const v4f*)srr[sub];
#pragma unroll
      for (int i = 0; i < 32; ++i) {
        v4f r0 = rq4[i * 2], r1 = rq4[i * 2 + 1];
        float a = bd + r0.x * wd[0] + r0.y * wd[1] + r0.z * wd[2]
                     + r0.w * wd[3] + r1.x * wd[4] + r1.y * wd[5];
        float ea = __expf(a);
        float p1 = rcp_f(1.f + ea);
        float dtv = (a > 20.f) ? a : -0.69314718055994531f * __log2f(p1);
        float dtx = dtv * xv[i];
        v2f dt2 = {dtx, dtx};
        float p2s = p1 * p1;
        v2f P1 = {p1, p2s};
        v2f P2 = P1 * (v2f){p2s, p2s};
        float p4s = P2.y;
        v2f P3 = P1 * (v2f){p4s, p4s};
        v2f P4 = P2 * (v2f){p4s, p4s};
        float p8s = P4.y;
        v2f P5 = P1 * (v2f){p8s, p8s};
        v2f P6 = P2 * (v2f){p8s, p8s};
        v2f P7 = P3 * (v2f){p8s, p8s};
        v2f P8 = P4 * (v2f){p8s, p8s};
        v4f B0 = bq4[i * 8 + 0], B1 = bq4[i * 8 + 1];
        v4f B2 = bq4[i * 8 + 2], B3 = bq4[i * 8 + 3];
        v4f C0 = bq4[i * 8 + 4], C1 = bq4[i * 8 + 5];
        v4f C2 = bq4[i * 8 + 6], C3 = bq4[i * 8 + 7];
        v2f y2;
        h2[0] = P1 * h2[0] + dt2 * SH2(B0, 0, 1); y2  = h2[0] * SH2(C0, 0, 1);
        h2[1] = P2 * h2[1] + dt2 * SH2(B0, 2, 3); y2 += h2[1] * SH2(C0, 2, 3);
        h2[2] = P3 * h2[2] + dt2 * SH2(B1, 0, 1); y2 += h2[2] * SH2(C1, 0, 1);
        h2[3] = P4 * h2[3] + dt2 * SH2(B1, 2, 3); y2 += h2[3] * SH2(C1, 2, 3);
        h2[4] = P5 * h2[4] + dt2 * SH2(B2, 0, 1); y2 += h2[4] * SH2(C2, 0, 1);
        h2[5] = P6 * h2[5] + dt2 * SH2(B2, 2, 3); y2 += h2[5] * SH2(C2, 2, 3);
        h2[6] = P7 * h2[6] + dt2 * SH2(B3, 0, 1); y2 += h2[6] * SH2(C3, 0, 1);
        h2[7] = P8 * h2[7] + dt2 * SH2(B3, 2, 3); y2 += h2[7] * SH2(C3, 2, 3);
        int qloc = k ? (31 - i) : i;
        yacc[qloc * 97 + d] = y2.x + y2.y + Dv * xv[i];
      }
    } else {
      float a2[16], hh[16];
#pragma unroll
      for (int n = 0; n < 16; ++n) { a2[n] = wb[A2OF + (k * 96 + d) * 16 + n]; hh[n] = hi[n]; }
#pragma unroll 4
      for (int i = 0; i < 32; ++i) {
        const float* rr = &srr[sub][i * 8];
        float a = bd + rr[0] * wd[0] + rr[1] * wd[1] + rr[2] * wd[2]
                     + rr[3] * wd[3] + rr[4] * wd[4] + rr[5] * wd[5];
        float dtv = (a > 20.f) ? a : log1pf(expf(a));
        float dtx = dtv * xv[i];
        const float* bcl = &sbc[sub][i * 32];
        float y = 0.f;
#pragma unroll
        for (int n = 0; n < 16; ++n) {
          hh[n] = exp2f(dtv * a2[n]) * hh[n] + dtx * bcl[n];
          y += hh[n] * bcl[16 + n];
        }
        int qloc = k ? (31 - i) : i;
        yacc[qloc * 97 + d] = y + Dv * xv[i];
      }
    }
  }
  __syncthreads();
  // parallel LN stats, conflict-free mapping: r=t&31, g=t>>5 (bit-identical sums)
  {
    float* p1 = &srr[0][0];          // 192 floats
    float* p2 = &srr[0][0] + 192;    // 192 floats (srr holds 512 total)
    int r = t & 31, c0 = (t >> 5) * 16;
    float s = 0, ss = 0;
#pragma unroll
    for (int j = 0; j < 16; ++j) {
      float v = yA[r * 97 + c0 + j] + yB[r * 97 + c0 + j];
      s += v; ss += v * v;
    }
    p1[t] = s; p2[t] = ss;
  }
  __syncthreads();
  if (t < 32) {
    const float* p1 = &srr[0][0];
    const float* p2 = &srr[0][0] + 192;
    float s = 0, ss = 0;
#pragma unroll
    for (int g = 0; g < 6; ++g) { s += p1[g * 32 + t]; ss += p2[g * 32 + t]; }
    float mu = s * (1.f / 96.f);
    float var = ss * (1.f / 96.f) - mu * mu;
    smu[t] = mu;
    srs[t] = rsqrtf(var + 1e-5f);
  }
  __syncthreads();
  {
    int r = t & 31, c0 = (t >> 5) * 16;
    int q = u * 32 + r;
    int p = sidx[b * LL + q];
    float mu = smu[r], rs = srs[r];
    float tmp[16];
#pragma unroll
    for (int j = 0; j < 16; ++j) {
      int dd = c0 + j;
      tmp[j] = (yA[r * 97 + dd] + yB[r * 97 + dd] - mu) * rs * wb[LN_G + dd] + wb[LN_B + dd];
    }
    float4* o4 = (float4*)(ymlm + ((size_t)b * LL + p) * 96 + c0);
    o4[0] = make_float4(tmp[0], tmp[1], tmp[2], tmp[3]);
    o4[1] = make_float4(tmp[4], tmp[5], tmp[6], tmp[7]);
    o4[2] = make_float4(tmp[8], tmp[9], tmp[10], tmp[11]);
    o4[3] = make_float4(tmp[12], tmp[13], tmp[14], tmp[15]);
  }
}

// ---------------- local conv + bias + BN stats (fused) ----------------
__global__ __launch_bounds__(256, 8)
void k_convlc_bn(const float* __restrict__ xconv, const float* __restrict__ wb,
                 float* __restrict__ lcbuf, float* __restrict__ stats) {
  int bd = blockIdx.x;
  int b = bd / 96, d = bd % 96;
  const float* src = xconv + (size_t)(b * 96 + d) * LL;
  const float* wr = wb + W_LOC + d * 9;
  float bias = wb[B_LOC + d];
  float s1 = 0, s2 = 0;
  for (int l = threadIdx.x; l < LL; l += 256) {
    int h = l / 48, w = l % 48;
    float acc = bias;
#pragma unroll
    for (int ki = 0; ki < 3; ++ki) {
      int hh = h + ki - 1; if (hh < 0 || hh >= 48) continue;
#pragma unroll
      for (int kj = 0; kj < 3; ++kj) {
        int ww = w + kj - 1; if (ww < 0 || ww >= 48) continue;
        acc += src[hh * 48 + ww] * wr[ki * 3 + kj];
      }
    }
    lcbuf[(size_t)(b * 96 + d) * LL + l] = acc;
    s1 += acc; s2 += acc * acc;
  }
  __shared__ float r1[256], r2[256];
  r1[threadIdx.x] = s1; r2[threadIdx.x] = s2; __syncthreads();
  for (int o = 128; o > 0; o >>= 1) {
    if (threadIdx.x < o) { r1[threadIdx.x] += r1[threadIdx.x + o]; r2[threadIdx.x] += r2[threadIdx.x + o]; }
    __syncthreads();
  }
  if (threadIdx.x == 0) { atomicAdd(&stats[d], r1[0]); atomicAdd(&stats[96 + d], r2[0]); }
}

// ---------------- final (acc-major, c-quarter x4, 128 thr; bnfin fused) ----------------
__global__ __launch_bounds__(128, 4)
void k_final(const float* __restrict__ lcbuf, const float* __restrict__ ymdm,
             const float* __restrict__ wb, const float* __restrict__ stats,
             void* __restrict__ out, const float* __restrict__ flag) {
  int b = blockIdx.x / 72;
  int rest = blockIdx.x % 72;
  int q = rest / 18;
  int l = (rest % 18) * 128 + threadIdx.x;
  float acc[24];
#pragma unroll
  for (int j = 0; j < 24; ++j) acc[j] = wb[B_OUT + q * 24 + j];
#pragma unroll 2
  for (int d = 0; d < 96; ++d) {
    float mean = stats[d] * (1.f / 73728.f);
    float var = stats[96 + d] * (1.f / 73728.f) - mean * mean;
    float sc = wb[BN_G + d] * rsqrtf(var + 1e-5f);
    float sh = wb[BN_B + d] - mean * sc;
    float lc = lcbuf[((size_t)b * 96 + d) * LL + l] * sc + sh;
    float vd = lc * rcp_f(1.f + __expf(-lc)) + ymdm[((size_t)b * 96 + d) * LL + l];
    const float* wr = wb + W_OUTT + d * 96 + q * 24;   // uniform -> s_load
#pragma unroll
    for (int j = 0; j < 24; ++j) acc[j] += vd * wr[j];
  }
  bool f = flag[0] > 0.5f;
  if (f) {
    float* of = (float*)out;
#pragma unroll
    for (int j = 0; j < 24; ++j) of[(b * 96 + q * 24 + j) * LL + l] = acc[j];
  } else {
    bf16* ob = (bf16*)out;
#pragma unroll
    for (int j = 0; j < 24; ++j) ob[(b * 96 + q * 24 + j) * LL + l] = __float2bfloat16(acc[j]);
  }
}

extern "C" void kernel_launch(void* const* d_in, const int* in_sizes, int n_in,
                              void* d_out, int out_size, void* d_ws, size_t ws_size,
                              hipStream_t stream) {
  if (ws_size < O_END * sizeof(float)) return;
  float* ws = (float*)d_ws;
  float* wb    = ws + O_WBUF;
  float* xfeat = ws + O_XFEAT;
  float* xconv = ws + O_XCONV;
  float* sim   = ws + O_SIM;
  int*   sidx  = (int*)(ws + O_SIDX);
  float* xst   = ws + O_XST;
  float* xstd  = ws + O_XSTD;
  float* rbuf  = ws + O_RBUF;
  float* bc    = ws + O_BC;
  float* dsum  = ws + O_DSUM;
  float* ymlm  = ws + O_YMLM;
  float* stats = ws + O_STATS;
  float* aflag = ws + O_AFLG;
  float* flag  = ws + O_FLAG;
  float* hend   = xfeat;   // xfeat dead after conv_silu
  float* hstart = xstd;    // xstd dead after xdbl
  float* ymdm   = xfeat;   // hend dead after scan2 read / scan3ln
  float* lcbuf  = xst;     // xst dead after scan3ln

  hipMemsetAsync(stats, 0, 256 * sizeof(float), stream);   // stats + aflag
  k_detect<<<1, 64, 0, stream>>>(d_in[0], flag);
  k_prep<<<36, 256, 0, stream>>>(
      d_in[1], d_in[2], d_in[5], d_in[6], d_in[7], d_in[8], d_in[9], d_in[10],
      d_in[11], d_in[12], d_in[13], d_in[14], d_in[15], d_in[16], d_in[17], d_in[18],
      d_in[19], wb, flag, aflag);
  k_inproj<<<2304, 128, 0, stream>>>(d_in[0], wb, xfeat, flag);
  k_conv_silu<<<6912, 256, 0, stream>>>(xfeat, wb, xconv);
  k_sim<<<288, 256, 0, stream>>>(xconv, sim);
  k_rank<<<1152, 256, 0, stream>>>(sim, sidx);
  k_gather2<<<1152, 256, 0, stream>>>(xconv, sidx, xstd, xst);
  k_xdbl<<<2304, 128, 0, stream>>>(xstd, wb, rbuf, bc);
  k_scan1<<<2304, 192, 0, stream>>>(rbuf, bc, xst, wb, dsum, hend, aflag);
  k_scan2<<<384, 256, 0, stream>>>(dsum, hend, wb, hstart);
  k_scan3ln<<<2304, 192, 0, stream>>>(rbuf, bc, xst, wb, hstart, sidx, ymlm, aflag);
  k_tr_ld<<<1152, 256, 0, stream>>>(ymlm, ymdm);
  k_convlc_bn<<<3072, 256, 0, stream>>>(xconv, wb, lcbuf, stats);
  k_final<<<2304, 128, 0, stream>>>(lcbuf, ymdm, wb, stats, d_out, flag);
}

// Round 16
// 510.746 us; speedup vs baseline: 1.0087x; 1.0087x over previous
//
#include <hip/hip_runtime.h>
#include <hip/hip_bf16.h>

// MambaSpatial: B=32, C_IN=D=96, H=W=48, L=2304, K=2, N=16, R=6.
// R4-R13: segmented scan (32-step, NSEG=72), native-transcendental scan math,
// packed v2f, xv[32] reg prefetch, O(L^2) rank argsort, channel-split x4
// inproj/final, fused gather2, parallel LN stats. R13 = 499.2us.
// R14 FAILED: de-LDS'd scans. R15: B-half staging, neutral.
// R16/R17 FAILED: (192,4) VGPR cap -> spill. R18 (502us): clean.
// R19 (515us): (a) xdbl 22/16 output-split 2304 blocks and (c) bnfin fused
//     into k_final SAVED ~30us combined, but (b) conv_silu 4-out/thread
//     REGRESSED 28 -> 73us (VGPR 12: register-starved serialized load
//     chain, VALUBusy 17.9% at 69% occupancy - no ILP).
// R20: revert conv_silu to 1-output/thread (27648 blocks, bit-identical,
//     restores sort-feeding numerics byte-for-byte). Keep (a) + (c).
// conv_silu/sim math deliberately UNCHANGED (feeds argsort; near-tie order).

typedef __hip_bfloat16 bf16;
typedef float v2f __attribute__((ext_vector_type(2)));
typedef float v4f __attribute__((ext_vector_type(4)));
#define SH2(V, a, b) __builtin_shufflevector(V, V, a, b)

__device__ __forceinline__ float b2f(bf16 v) { return __bfloat162float(v); }
__device__ __forceinline__ float ldu(const void* p, int i, bool f32) {
  if (f32) return ((const float*)p)[i];
  return b2f(((const bf16*)p)[i]);
}
__device__ __forceinline__ float rcp_f(float x) { return __builtin_amdgcn_rcpf(x); }

#define LL 2304
#define NSEG 72          // 32-step segments

// ---- wbuf offsets (floats) ----
#define W_INT  0        // in_proj_w transposed [c][d] 9216
#define B_IN   9216
#define W_C2D  9312
#define B_C2D  10176
#define W_LOC  10272
#define B_LOC  11136
#define BN_G   11232
#define BN_B   11328
#define W_XPT  11424    // x_proj_w transposed [d][80]
#define W_DT   19104    // dt_projs_w [k][d][6]
#define B_DT   20256
#define A2OF   20448    // -exp(A_logs)*log2(e) [k][d][16]
#define DSOF   23520
#define LN_G   23712
#define LN_B   23808
#define W_OUTT 23904    // out_proj_w transposed [d][c]
#define B_OUT  33120
#define WBUF_N 33280ul

// ---- workspace layout (float offsets) ----
#define O_WBUF  0ul
#define O_XFEAT 33280ul        // 7,077,888 ; reused: hend ; then ymdm
#define O_XCONV 7111168ul      // 7,077,888
#define O_SIM   14189056ul
#define O_SIDX  14262784ul
#define O_XST   14336512ul     // sorted l-major [b][l][d] ; reused: lcbuf
#define O_XSTD  21414400ul     // sorted d-major [b][d][l] ; reused: hstart
#define O_RBUF  28492288ul     // [b][k][l][8]
#define O_BC    29671936ul     // [b][k][l][32]
#define O_DSUM  34390528ul     // [b][k][d][72] 442,368
#define O_YMLM  34832896ul     // [b][p][96] 7,077,888
#define O_STATS 41910784ul
#define O_AFLG  41910976ul
#define O_SCSH  41911040ul
#define O_FLAG  41911232ul
#define O_END   41911296ul     // ~167.6 MB

// ---------------- dtype detect ----------------
__global__ void k_detect(const void* x, float* flag) {
  int i = threadIdx.x;
  bool bad = false;
  const bf16* xb = (const bf16*)x;
#pragma unroll
  for (int r = 0; r < 4; ++r) {
    float v = b2f(xb[r * 64 + i]);
    if (!(fabsf(v) <= 1e4f)) bad = true;
  }
  bool any = __any(bad);
  if (i == 0) flag[0] = any ? 1.f : 0.f;
}

// ---------------- prep ----------------
__global__ void k_prep(const void* ipw, const void* ipb, const void* c2w, const void* c2b,
                       const void* lw, const void* lb, const void* bng, const void* bnb,
                       const void* xpw, const void* dtw, const void* dtb, const void* alog,
                       const void* dss, const void* ng, const void* nb, const void* opw,
                       const void* opb, float* wb, const float* flag, float* aflag) {
  bool f = flag[0] > 0.5f;
  int i = blockIdx.x * 256 + threadIdx.x;
  if (i < 9216) {
    int r = i / 96, c = i % 96;
    wb[W_INT + c * 96 + r] = ldu(ipw, i, f);
    wb[W_OUTT + c * 96 + r] = ldu(opw, i, f);
  }
  if (i < 96) {
    wb[B_IN + i] = ldu(ipb, i, f); wb[B_C2D + i] = ldu(c2b, i, f); wb[B_LOC + i] = ldu(lb, i, f);
    wb[BN_G + i] = ldu(bng, i, f); wb[BN_B + i] = ldu(bnb, i, f); wb[LN_G + i] = ldu(ng, i, f);
    wb[LN_B + i] = ldu(nb, i, f); wb[B_OUT + i] = ldu(opb, i, f);
  }
  if (i < 864) { wb[W_C2D + i] = ldu(c2w, i, f); wb[W_LOC + i] = ldu(lw, i, f); }
  if (i < 7296) {
    int k = i / 3648, c = (i / 96) % 38, d = i % 96;
    wb[W_XPT + d * 80 + k * 38 + c] = ldu(xpw, i, f);
  }
  if (i < 1152) wb[W_DT + i] = ldu(dtw, i, f);
  if (i < 192) { wb[B_DT + i] = ldu(dtb, i, f); wb[DSOF + i] = ldu(dss, i, f); }
  if (i < 3072) {
    float av = expf(ldu(alog, i, f));
    wb[A2OF + i] = -av * 1.4426950408889634f;
    int n = i % 16;
    if (fabsf(av - (float)(n + 1)) > 1e-3f * (n + 1)) atomicAdd(aflag, 1.f);
  }
}

// ---------------- in_proj (acc-major, d-quarter x4, 128 thr) ----------------
__global__ __launch_bounds__(128, 4)
void k_inproj(const void* __restrict__ x, const float* __restrict__ wb,
              float* __restrict__ xfeat, const float* __restrict__ flag) {
  int b = blockIdx.x / 72;
  int rest = blockIdx.x % 72;
  int q = rest / 18;
  int l = (rest % 18) * 128 + threadIdx.x;
  float acc[24];
#pragma unroll
  for (int j = 0; j < 24; ++j) acc[j] = wb[B_IN + q * 24 + j];
  bool f = flag[0] > 0.5f;
  if (f) {
    const float* xf = (const float*)x;
#pragma unroll 2
    for (int c = 0; c < 96; ++c) {
      float xc = xf[(b * 96 + c) * LL + l];
      const float* wr = wb + W_INT + c * 96 + q * 24;
#pragma unroll
      for (int j = 0; j < 24; ++j) acc[j] += xc * wr[j];
    }
  } else {
    const bf16* xb = (const bf16*)x;
#pragma unroll 2
    for (int c = 0; c < 96; ++c) {
      float xc = b2f(xb[(b * 96 + c) * LL + l]);
      const float* wr = wb + W_INT + c * 96 + q * 24;
#pragma unroll
      for (int j = 0; j < 24; ++j) acc[j] += xc * wr[j];
    }
  }
#pragma unroll
  for (int j = 0; j < 24; ++j) xfeat[(b * 96 + q * 24 + j) * LL + l] = acc[j];
}

// ---------------- depthwise 3x3 + bias + silu (1 output/thread) ----------------
__global__ __launch_bounds__(256, 8)
void k_conv_silu(const float* __restrict__ xfeat, const float* __restrict__ wb,
                 float* __restrict__ xconv) {
  int t = blockIdx.x * 256 + threadIdx.x;
  int l = t % LL; int d = (t / LL) % 96; int b = t / (LL * 96);
  int h = l / 48, w = l % 48;
  const float* wr = wb + W_C2D + d * 9;
  const float* src = xfeat + (b * 96 + d) * LL;
  float acc = wb[B_C2D + d];
#pragma unroll
  for (int ki = 0; ki < 3; ++ki) {
    int hh = h + ki - 1; if (hh < 0 || hh >= 48) continue;
#pragma unroll
    for (int kj = 0; kj < 3; ++kj) {
      int ww = w + kj - 1; if (ww < 0 || ww >= 48) continue;
      acc += src[hh * 48 + ww] * wr[ki * 3 + kj];
    }
  }
  xconv[t] = acc / (1.f + expf(-acc));
}

// ---------------- cosine-sim vs center pixel ----------------
__global__ __launch_bounds__(256, 8)
void k_sim(const float* __restrict__ xconv, float* __restrict__ sim) {
  int b = blockIdx.x / 9;
  int l = (blockIdx.x % 9) * 256 + threadIdx.x;
  const float* base = xconv + (size_t)b * 96 * LL;
  float dot = 0, nrm = 0, cn = 0;
  for (int d = 0; d < 96; ++d) {
    float v = base[d * LL + l];
    float c = base[d * LL + 1176];
    dot += v * c; nrm += v * v; cn += c * c;
  }
  float den = fmaxf(sqrtf(nrm), 1e-12f) * fmaxf(sqrtf(cn), 1e-12f);
  sim[b * LL + l] = dot / den;
}

// ---------------- stable argsort desc via O(L^2) rank-by-count ----------------
__global__ __launch_bounds__(256, 8)
void k_rank(const float* __restrict__ sim, int* __restrict__ sidx) {
  __shared__ unsigned su[LL];
  int b = blockIdx.x / 36;
  int part = blockIdx.x % 36;
  const float* sp = sim + b * LL;
  for (int i = threadIdx.x; i < LL; i += 256) {
    unsigned u = __float_as_uint(sp[i]);
    u = (u >> 31) ? ~u : (u | 0x80000000u);
    su[i] = u;
  }
  __syncthreads();
  int lq = threadIdx.x >> 2;           // 0..63: element within part
  int ch = threadIdx.x & 3;            // 0..3: j-chunk
  int l = part * 64 + lq;
  unsigned ui = su[l];
  int rank = 0;
  const uint4* s4 = (const uint4*)su;
#pragma unroll 4
  for (int it = 0; it < 144; ++it) {
    int m = 4 * it + ch;
    uint4 U = s4[m];
    int j = 4 * m;
    rank += (int)(U.x > ui) + (int)((U.x == ui) & (j + 0 < l));
    rank += (int)(U.y > ui) + (int)((U.y == ui) & (j + 1 < l));
    rank += (int)(U.z > ui) + (int)((U.z == ui) & (j + 2 < l));
    rank += (int)(U.w > ui) + (int)((U.w == ui) & (j + 3 < l));
  }
  rank += __shfl_xor(rank, 1);
  rank += __shfl_xor(rank, 2);
  if (ch == 0) sidx[b * LL + rank] = l;
}

// ---------------- fused gather + transpose: xconv -> xstd (d-major) + xst (l-major) ----------------
__global__ __launch_bounds__(256, 4)
void k_gather2(const float* __restrict__ xconv, const int* __restrict__ sidx,
               float* __restrict__ xstd, float* __restrict__ xst) {
  __shared__ float tile[64 * 97];
  __shared__ int sp[64];
  int b = blockIdx.x / 36;
  int l0 = (blockIdx.x % 36) * 64;
  if (threadIdx.x < 64) sp[threadIdx.x] = sidx[b * LL + l0 + threadIdx.x];
  __syncthreads();
  const float* base = xconv + (size_t)b * 96 * LL;
#pragma unroll
  for (int it = 0; it < 24; ++it) {
    int idx = it * 256 + threadIdx.x;
    int d = idx / 64, j = idx % 64;
    tile[j * 97 + d] = base[d * LL + sp[j]];
  }
  __syncthreads();
#pragma unroll
  for (int it = 0; it < 24; ++it) {
    int idx = it * 256 + threadIdx.x;
    int r = idx / 96, c = idx % 96;
    xst[((size_t)b * LL + l0 + r) * 96 + c] = tile[r * 97 + c];
  }
#pragma unroll
  for (int it = 0; it < 24; ++it) {
    int idx = it * 256 + threadIdx.x;
    int d = idx / 64, j = idx % 64;
    xstd[((size_t)b * 96 + d) * LL + l0 + j] = tile[j * 97 + d];
  }
}

// ---------------- transpose l-major -> d-major (ymlm -> ymdm) ----------------
__global__ __launch_bounds__(256, 4)
void k_tr_ld(const float* __restrict__ in, float* __restrict__ out) {
  __shared__ float tile[64 * 97];
  int b = blockIdx.x / 36;
  int l0 = (blockIdx.x % 36) * 64;
#pragma unroll
  for (int it = 0; it < 24; ++it) {
    int idx = it * 256 + threadIdx.x;
    int r = idx / 96, c = idx % 96;
    tile[r * 97 + c] = in[((size_t)b * LL + l0 + r) * 96 + c];
  }
  __syncthreads();
#pragma unroll
  for (int it = 0; it < 24; ++it) {
    int idx = it * 256 + threadIdx.x;
    int d = idx / 64, j = idx % 64;
    out[((size_t)b * 96 + d) * LL + l0 + j] = tile[j * 97 + d];
  }
}

// ---------------- x_dbl, output-split 22/16, one 2304-block launch ----------------
__global__ __launch_bounds__(128, 4)
void k_xdbl(const float* __restrict__ xstd, const float* __restrict__ wb,
            float* __restrict__ rbuf, float* __restrict__ bc) {
  int half = blockIdx.x / 1152;
  int r2 = blockIdx.x % 1152;
  int kq = r2 / 576;
  int r = r2 % 576;
  int b = r / 18;
  int l = (r % 18) * 128 + threadIdx.x;
  int lout = kq ? (LL - 1 - l) : l;
  if (half == 0) {
    float acc[22];
#pragma unroll
    for (int j = 0; j < 22; ++j) acc[j] = 0.f;
#pragma unroll 2
    for (int c = 0; c < 96; ++c) {
      float xc = xstd[((size_t)b * 96 + c) * LL + l];
      const float* wr = wb + W_XPT + c * 80 + kq * 38;   // uniform -> s_load
#pragma unroll
      for (int j = 0; j < 22; ++j) acc[j] += xc * wr[j];
    }
    float4* r4 = (float4*)(rbuf + ((size_t)(b * 2 + kq) * LL + lout) * 8);
    r4[0] = make_float4(acc[0], acc[1], acc[2], acc[3]);
    r4[1] = make_float4(acc[4], acc[5], 0.f, 0.f);
    float4* b4 = (float4*)(bc + ((size_t)(b * 2 + kq) * LL + lout) * 32);
#pragma unroll
    for (int i = 0; i < 4; ++i)
      b4[i] = make_float4(acc[6 + 4 * i], acc[7 + 4 * i], acc[8 + 4 * i], acc[9 + 4 * i]);
  } else {
    float acc[16];
#pragma unroll
    for (int j = 0; j < 16; ++j) acc[j] = 0.f;
#pragma unroll 2
    for (int c = 0; c < 96; ++c) {
      float xc = xstd[((size_t)b * 96 + c) * LL + l];
      const float* wr = wb + W_XPT + c * 80 + kq * 38 + 22;
#pragma unroll
      for (int j = 0; j < 16; ++j) acc[j] += xc * wr[j];
    }
    float4* b4 = (float4*)(bc + ((size_t)(b * 2 + kq) * LL + lout) * 32);
#pragma unroll
    for (int i = 0; i < 4; ++i)
      b4[4 + i] = make_float4(acc[4 * i], acc[4 * i + 1], acc[4 * i + 2], acc[4 * i + 3]);
  }
}

// ---------------- scan pass 1: 32-step segments, LDS-staged B-half + rr ----------------
__global__ __launch_bounds__(192, 3)
void k_scan1(const float* __restrict__ rbuf, const float* __restrict__ bc,
             const float* __restrict__ xst, const float* __restrict__ wb,
             float* __restrict__ dsum, float* __restrict__ hend,
             const float* __restrict__ aflag) {
  __shared__ float sbc[2][512];
  __shared__ float srr[2][256];
  int sub = threadIdx.x / 96;
  int tid = threadIdx.x - sub * 96;
  int unit = blockIdx.x * 2 + sub;             // b*144 + k*72 + s
  int s = unit % 72; int k = (unit / 72) % 2; int b = unit / 144;
  int lbase = (b * 2 + k) * LL + s * 32;
  long long lk0 = k ? (LL - 1 - s * 32) : (s * 32);
  long long stp = k ? -96 : 96;
  const float* xp = xst + (size_t)b * LL * 96 + lk0 * 96 + tid;
  float xv[32];
#pragma unroll
  for (int t = 0; t < 32; ++t) xv[t] = xp[t * stp];
  {
    const float4* bsrc = (const float4*)(bc + (size_t)lbase * 32);
    float4* bdst = (float4*)sbc[sub];
    for (int i = tid; i < 128; i += 96) {
      int l = i >> 2, c = i & 3;
      bdst[i] = bsrc[l * 8 + c];     // B-half: first 4 of 8 chunks per l
    }
    const float4* rsrc = (const float4*)(rbuf + (size_t)lbase * 8);
    float4* rdst = (float4*)srr[sub];
    if (tid < 64) rdst[tid] = rsrc[tid];
  }
  __syncthreads();
  int d = tid;
  float wd[6];
#pragma unroll
  for (int j = 0; j < 6; ++j) wd[j] = wb[W_DT + (k * 96 + d) * 6 + j];
  float bd = wb[B_DT + k * 96 + d];
  float ds = 0.f;
  v2f h2[8];
#pragma unroll
  for (int j = 0; j < 8; ++j) h2[j] = (v2f){0.f, 0.f};
  bool fast = (aflag[0] == 0.f);
  if (fast) {
    const v4f* bq4 = (const v4f*)sbc[sub];
    const v4f* rq4 = (const v4f*)srr[sub];
#pragma unroll
    for (int t = 0; t < 32; ++t) {
      v4f r0 = rq4[t * 2], r1 = rq4[t * 2 + 1];
      float a = bd + r0.x * wd[0] + r0.y * wd[1] + r0.z * wd[2]
                   + r0.w * wd[3] + r1.x * wd[4] + r1.y * wd[5];
      float ea = __expf(a);
      float p1 = rcp_f(1.f + ea);
      float dtv = (a > 20.f) ? a : -0.69314718055994531f * __log2f(p1);
      ds += dtv;
      float dtx = dtv * xv[t];
      v2f dt2 = {dtx, dtx};
      float p2s = p1 * p1;
      v2f P1 = {p1, p2s};
      v2f P2 = P1 * (v2f){p2s, p2s};        // p3,p4
      float p4s = P2.y;
      v2f P3 = P1 * (v2f){p4s, p4s};        // p5,p6
      v2f P4 = P2 * (v2f){p4s, p4s};        // p7,p8
      float p8s = P4.y;
      v2f P5 = P1 * (v2f){p8s, p8s};        // p9,p10
      v2f P6 = P2 * (v2f){p8s, p8s};        // p11,p12
      v2f P7 = P3 * (v2f){p8s, p8s};        // p13,p14
      v2f P8 = P4 * (v2f){p8s, p8s};        // p15,p16
      v4f B0 = bq4[t * 4 + 0], B1 = bq4[t * 4 + 1];
      v4f B2 = bq4[t * 4 + 2], B3 = bq4[t * 4 + 3];
      h2[0] = P1 * h2[0] + dt2 * SH2(B0, 0, 1);
      h2[1] = P2 * h2[1] + dt2 * SH2(B0, 2, 3);
      h2[2] = P3 * h2[2] + dt2 * SH2(B1, 0, 1);
      h2[3] = P4 * h2[3] + dt2 * SH2(B1, 2, 3);
      h2[4] = P5 * h2[4] + dt2 * SH2(B2, 0, 1);
      h2[5] = P6 * h2[5] + dt2 * SH2(B2, 2, 3);
      h2[6] = P7 * h2[6] + dt2 * SH2(B3, 0, 1);
      h2[7] = P8 * h2[7] + dt2 * SH2(B3, 2, 3);
    }
  } else {
    float a2[16], hh[16];
#pragma unroll
    for (int n = 0; n < 16; ++n) { a2[n] = wb[A2OF + (k * 96 + d) * 16 + n]; hh[n] = 0.f; }
#pragma unroll 4
    for (int t = 0; t < 32; ++t) {
      const float* rr = &srr[sub][t * 8];
      float a = bd + rr[0] * wd[0] + rr[1] * wd[1] + rr[2] * wd[2]
                   + rr[3] * wd[3] + rr[4] * wd[4] + rr[5] * wd[5];
      float dtv = (a > 20.f) ? a : log1pf(expf(a));
      ds += dtv;
      float dtx = dtv * xv[t];
      const float* bcl = &sbc[sub][t * 16];
#pragma unroll
      for (int n = 0; n < 16; ++n) hh[n] = exp2f(dtv * a2[n]) * hh[n] + dtx * bcl[n];
    }
#pragma unroll
    for (int j = 0; j < 8; ++j) h2[j] = (v2f){hh[2 * j], hh[2 * j + 1]};
  }
  dsum[((b * 2 + k) * 96 + d) * NSEG + s] = ds;
  float4* ho = (float4*)(hend + (((size_t)(b * 2 + k) * NSEG + s) * 96 + d) * 16);
  ho[0] = make_float4(h2[0].x, h2[0].y, h2[1].x, h2[1].y);
  ho[1] = make_float4(h2[2].x, h2[2].y, h2[3].x, h2[3].y);
  ho[2] = make_float4(h2[4].x, h2[4].y, h2[5].x, h2[5].y);
  ho[3] = make_float4(h2[6].x, h2[6].y, h2[7].x, h2[7].y);
}

// ---------------- scan pass 2: stitch 72 segments ----------------
__global__ __launch_bounds__(256, 4)
void k_scan2(const float* __restrict__ dsum, const float* __restrict__ hend,
             const float* __restrict__ wb, float* __restrict__ hstart) {
  int t = blockIdx.x * 256 + threadIdx.x;
  int n = t % 16; int d = (t / 16) % 96; int k = (t / 1536) % 2; int b = t / 3072;
  float a2 = wb[A2OF + (k * 96 + d) * 16 + n];
  float h = 0.f;
  int rowd = ((b * 2 + k) * 96 + d) * NSEG;
#pragma unroll 8
  for (int s = 0; s < NSEG; ++s) {
    size_t idx = (((size_t)(b * 2 + k) * NSEG + s) * 96 + d) * 16 + n;
    hstart[idx] = h;
    h = exp2f(a2 * dsum[rowd + s]) * h + hend[idx];
  }
}

// ---------------- scan3 + combine + LN (32-row tiles, staged) ----------------
__global__ __launch_bounds__(192, 3)
void k_scan3ln(const float* __restrict__ rbuf, const float* __restrict__ bc,
               const float* __restrict__ xst, const float* __restrict__ wb,
               const float* __restrict__ hstart, const int* __restrict__ sidx,
               float* __restrict__ ymlm, const float* __restrict__ aflag) {
  __shared__ float yA[32 * 97];
  __shared__ float yB[32 * 97];
  __shared__ float sbc[2][1024];
  __shared__ float srr[2][256];
  __shared__ float smu[32], srs[32];
  int b = blockIdx.x / NSEG;
  int u = blockIdx.x % NSEG;
  int t = threadIdx.x;
  int sub = t / 96;                      // sub==k
  int d = t - sub * 96;
  int k = sub;
  int seg = sub ? (NSEG - 1 - u) : u;
  int lbase = (b * 2 + k) * LL + seg * 32;
  long long lk0 = k ? (LL - 1 - seg * 32) : (seg * 32);
  long long stp = k ? -96 : 96;
  const float* xp = xst + (size_t)b * LL * 96 + lk0 * 96 + d;
  float xv[32];
#pragma unroll
  for (int i = 0; i < 32; ++i) xv[i] = xp[i * stp];
  {
    const float4* bsrc = (const float4*)(bc + (size_t)lbase * 32);
    float4* bdst = (float4*)sbc[sub];
    for (int i = d; i < 256; i += 96) bdst[i] = bsrc[i];
    const float4* rsrc = (const float4*)(rbuf + (size_t)lbase * 8);
    float4* rdst = (float4*)srr[sub];
    if (d < 64) rdst[d] = rsrc[d];
  }
  __syncthreads();
  {
    float* yacc = sub ? yB : yA;
    float wd[6];
#pragma unroll
    for (int j = 0; j < 6; ++j) wd[j] = wb[W_DT + (k * 96 + d) * 6 + j];
    float bd = wb[B_DT + k * 96 + d];
    float Dv = wb[DSOF + k * 96 + d];
    const float* hi = hstart + (((size_t)(b * 2 + k) * NSEG + seg) * 96 + d) * 16;
    bool fast = (aflag[0] == 0.f);
    if (fast) {
      const v4f* hi4 = (const v4f*)hi;
      v4f H0 = hi4[0], H1 = hi4[1], H2 = hi4[2], H3 = hi4[3];
      v2f h2[8];
      h2[0] = SH2(H0, 0, 1); h2[1] = SH2(H0, 2, 3);
      h2[2] = SH2(H1, 0, 1); h2[3] = SH2(H1, 2, 3);
      h2[4] = SH2(H2, 0, 1); h2[5] = SH2(H2, 2, 3);
      h2[6] = SH2(H3, 0, 1); h2[7] = SH2(H3, 2, 3);
      const v4f* bq4 = (const v4f*)sbc[sub];
      const v4f* rq4 = (const v4f*)srr[sub];
#pragma unroll
      for (int i = 0; i < 32; ++i) {
        v4f r0 = rq4[i * 2], r1 = rq4[i * 2 + 1];
        float a = bd + r0.x * wd[0] + r0.y * wd[1] + r0.z * wd[2]
                     + r0.w * wd[3] + r1.x * wd[4] + r1.y * wd[5];
        float ea = __expf(a);
        float p1 = rcp_f(1.f + ea);
        float dtv = (a > 20.f) ? a : -0.69314718055994531f * __log2f(p1);
        float dtx = dtv * xv[i];
        v2f dt2 = {dtx, dtx};
        float p2s = p1 * p1;
        v2f P1 = {p1, p2s};
        v2f P2 = P1 * (v2f){p2s, p2s};
        float p4s = P2.y;
        v2f P3 = P1 * (v2f){p4s, p4s};
        v2f P4 = P2 * (v2f){p4s, p4s};
        float p8s = P4.y;
        v2f P5 = P1 * (v2f){p8s, p8s};
        v2f P6 = P2 * (v2f){p8s, p8s};
        v2f P7 = P3 * (v2f){p8s, p8s};
        v2f P8 = P4 * (v2f){p8s, p8s};
        v4f B0 = bq4[i * 8 + 0], B1 = bq4[i * 8 + 1];
        v4f B2 = bq4[i * 8 + 2], B3 = bq4[i * 8 + 3];
        v4f C0 = bq4[i * 8 + 4], C1 = bq4[i * 8 + 5];
        v4f C2 = bq4[i * 8 + 6], C3 = bq4[i * 8 + 7];
        v2f y2;
        h2[0] = P1 * h2[0] + dt2 * SH2(B0, 0, 1); y2  = h2[0] * SH2(C0, 0, 1);
        h2[1] = P2 * h2[1] + dt2 * SH2(B0, 2, 3); y2 += h2[1] * SH2(C0, 2, 3);
        h2[2] = P3 * h2[2] + dt2 * SH2(B1, 0, 1); y2 += h2[2] * SH2(C1, 0, 1);
        h2[3] = P4 * h2[3] + dt2 * SH2(B1, 2, 3); y2 += h2[3] * SH2(C1, 2, 3);
        h2[4] = P5 * h2[4] + dt2 * SH2(B2, 0, 1); y2 += h2[4] * SH2(C2, 0, 1);
        h2[5] = P6 * h2[5] + dt2 * SH2(B2, 2, 3); y2 += h2[5] * SH2(C2, 2, 3);
        h2[6] = P7 * h2[6] + dt2 * SH2(B3, 0, 1); y2 += h2[6] * SH2(C3, 0, 1);
        h2[7] = P8 * h2[7] + dt2 * SH2(B3, 2, 3); y2 += h2[7] * SH2(C3, 2, 3);
        int qloc = k ? (31 - i) : i;
        yacc[qloc * 97 + d] = y2.x + y2.y + Dv * xv[i];
      }
    } else {
      float a2[16], hh[16];
#pragma unroll
      for (int n = 0; n < 16; ++n) { a2[n] = wb[A2OF + (k * 96 + d) * 16 + n]; hh[n] = hi[n]; }
#pragma unroll 4
      for (int i = 0; i < 32; ++i) {
        const float* rr = &srr[sub][i * 8];
        float a = bd + rr[0] * wd[0] + rr[1] * wd[1] + rr[2] * wd[2]
                     + rr[3] * wd[3] + rr[4] * wd[4] + rr[5] * wd[5];
        float dtv = (a > 20.f) ? a : log1pf(expf(a));
        float dtx = dtv * xv[i];
        const float* bcl = &sbc[sub][i * 32];
        float y = 0.f;
#pragma unroll
        for (int n = 0; n < 16; ++n) {
          hh[n] = exp2f(dtv * a2[n]) * hh[n] + dtx * bcl[n];
          y += hh[n] * bcl[16 + n];
        }
        int qloc = k ? (31 - i) : i;
        yacc[qloc * 97 + d] = y + Dv * xv[i];
      }
    }
  }
  __syncthreads();
  // parallel LN stats, conflict-free mapping: r=t&31, g=t>>5 (bit-identical sums)
  {
    float* p1 = &srr[0][0];          // 192 floats
    float* p2 = &srr[0][0] + 192;    // 192 floats (srr holds 512 total)
    int r = t & 31, c0 = (t >> 5) * 16;
    float s = 0, ss = 0;
#pragma unroll
    for (int j = 0; j < 16; ++j) {
      float v = yA[r * 97 + c0 + j] + yB[r * 97 + c0 + j];
      s += v; ss += v * v;
    }
    p1[t] = s; p2[t] = ss;
  }
  __syncthreads();
  if (t < 32) {
    const float* p1 = &srr[0][0];
    const float* p2 = &srr[0][0] + 192;
    float s = 0, ss = 0;
#pragma unroll
    for (int g = 0; g < 6; ++g) { s += p1[g * 32 + t]; ss += p2[g * 32 + t]; }
    float mu = s * (1.f / 96.f);
    float var = ss * (1.f / 96.f) - mu * mu;
    smu[t] = mu;
    srs[t] = rsqrtf(var + 1e-5f);
  }
  __syncthreads();
  {
    int r = t & 31, c0 = (t >> 5) * 16;
    int q = u * 32 + r;
    int p = sidx[b * LL + q];
    float mu = smu[r], rs = srs[r];
    float tmp[16];
#pragma unroll
    for (int j = 0; j < 16; ++j) {
      int dd = c0 + j;
      tmp[j] = (yA[r * 97 + dd] + yB[r * 97 + dd] - mu) * rs * wb[LN_G + dd] + wb[LN_B + dd];
    }
    float4* o4 = (float4*)(ymlm + ((size_t)b * LL + p) * 96 + c0);
    o4[0] = make_float4(tmp[0], tmp[1], tmp[2], tmp[3]);
    o4[1] = make_float4(tmp[4], tmp[5], tmp[6], tmp[7]);
    o4[2] = make_float4(tmp[8], tmp[9], tmp[10], tmp[11]);
    o4[3] = make_float4(tmp[12], tmp[13], tmp[14], tmp[15]);
  }
}

// ---------------- local conv + bias + BN stats (fused) ----------------
__global__ __launch_bounds__(256, 8)
void k_convlc_bn(const float* __restrict__ xconv, const float* __restrict__ wb,
                 float* __restrict__ lcbuf, float* __restrict__ stats) {
  int bd = blockIdx.x;
  int b = bd / 96, d = bd % 96;
  const float* src = xconv + (size_t)(b * 96 + d) * LL;
  const float* wr = wb + W_LOC + d * 9;
  float bias = wb[B_LOC + d];
  float s1 = 0, s2 = 0;
  for (int l = threadIdx.x; l < LL; l += 256) {
    int h = l / 48, w = l % 48;
    float acc = bias;
#pragma unroll
    for (int ki = 0; ki < 3; ++ki) {
      int hh = h + ki - 1; if (hh < 0 || hh >= 48) continue;
#pragma unroll
      for (int kj = 0; kj < 3; ++kj) {
        int ww = w + kj - 1; if (ww < 0 || ww >= 48) continue;
        acc += src[hh * 48 + ww] * wr[ki * 3 + kj];
      }
    }
    lcbuf[(size_t)(b * 96 + d) * LL + l] = acc;
    s1 += acc; s2 += acc * acc;
  }
  __shared__ float r1[256], r2[256];
  r1[threadIdx.x] = s1; r2[threadIdx.x] = s2; __syncthreads();
  for (int o = 128; o > 0; o >>= 1) {
    if (threadIdx.x < o) { r1[threadIdx.x] += r1[threadIdx.x + o]; r2[threadIdx.x] += r2[threadIdx.x + o]; }
    __syncthreads();
  }
  if (threadIdx.x == 0) { atomicAdd(&stats[d], r1[0]); atomicAdd(&stats[96 + d], r2[0]); }
}

// ---------------- final (acc-major, c-quarter x4, 128 thr; bnfin fused) ----------------
__global__ __launch_bounds__(128, 4)
void k_final(const float* __restrict__ lcbuf, const float* __restrict__ ymdm,
             const float* __restrict__ wb, const float* __restrict__ stats,
             void* __restrict__ out, const float* __restrict__ flag) {
  int b = blockIdx.x / 72;
  int rest = blockIdx.x % 72;
  int q = rest / 18;
  int l = (rest % 18) * 128 + threadIdx.x;
  float acc[24];
#pragma unroll
  for (int j = 0; j < 24; ++j) acc[j] = wb[B_OUT + q * 24 + j];
#pragma unroll 2
  for (int d = 0; d < 96; ++d) {
    float mean = stats[d] * (1.f / 73728.f);
    float var = stats[96 + d] * (1.f / 73728.f) - mean * mean;
    float sc = wb[BN_G + d] * rsqrtf(var + 1e-5f);
    float sh = wb[BN_B + d] - mean * sc;
    float lc = lcbuf[((size_t)b * 96 + d) * LL + l] * sc + sh;
    float vd = lc * rcp_f(1.f + __expf(-lc)) + ymdm[((size_t)b * 96 + d) * LL + l];
    const float* wr = wb + W_OUTT + d * 96 + q * 24;   // uniform -> s_load
#pragma unroll
    for (int j = 0; j < 24; ++j) acc[j] += vd * wr[j];
  }
  bool f = flag[0] > 0.5f;
  if (f) {
    float* of = (float*)out;
#pragma unroll
    for (int j = 0; j < 24; ++j) of[(b * 96 + q * 24 + j) * LL + l] = acc[j];
  } else {
    bf16* ob = (bf16*)out;
#pragma unroll
    for (int j = 0; j < 24; ++j) ob[(b * 96 + q * 24 + j) * LL + l] = __float2bfloat16(acc[j]);
  }
}

extern "C" void kernel_launch(void* const* d_in, const int* in_sizes, int n_in,
                              void* d_out, int out_size, void* d_ws, size_t ws_size,
                              hipStream_t stream) {
  if (ws_size < O_END * sizeof(float)) return;
  float* ws = (float*)d_ws;
  float* wb    = ws + O_WBUF;
  float* xfeat = ws + O_XFEAT;
  float* xconv = ws + O_XCONV;
  float* sim   = ws + O_SIM;
  int*   sidx  = (int*)(ws + O_SIDX);
  float* xst   = ws + O_XST;
  float* xstd  = ws + O_XSTD;
  float* rbuf  = ws + O_RBUF;
  float* bc    = ws + O_BC;
  float* dsum  = ws + O_DSUM;
  float* ymlm  = ws + O_YMLM;
  float* stats = ws + O_STATS;
  float* aflag = ws + O_AFLG;
  float* flag  = ws + O_FLAG;
  float* hend   = xfeat;   // xfeat dead after conv_silu
  float* hstart = xstd;    // xstd dead after xdbl
  float* ymdm   = xfeat;   // hend dead after scan2 read / scan3ln
  float* lcbuf  = xst;     // xst dead after scan3ln

  hipMemsetAsync(stats, 0, 256 * sizeof(float), stream);   // stats + aflag
  k_detect<<<1, 64, 0, stream>>>(d_in[0], flag);
  k_prep<<<36, 256, 0, stream>>>(
      d_in[1], d_in[2], d_in[5], d_in[6], d_in[7], d_in[8], d_in[9], d_in[10],
      d_in[11], d_in[12], d_in[13], d_in[14], d_in[15], d_in[16], d_in[17], d_in[18],
      d_in[19], wb, flag, aflag);
  k_inproj<<<2304, 128, 0, stream>>>(d_in[0], wb, xfeat, flag);
  k_conv_silu<<<27648, 256, 0, stream>>>(xfeat, wb, xconv);
  k_sim<<<288, 256, 0, stream>>>(xconv, sim);
  k_rank<<<1152, 256, 0, stream>>>(sim, sidx);
  k_gather2<<<1152, 256, 0, stream>>>(xconv, sidx, xstd, xst);
  k_xdbl<<<2304, 128, 0, stream>>>(xstd, wb, rbuf, bc);
  k_scan1<<<2304, 192, 0, stream>>>(rbuf, bc, xst, wb, dsum, hend, aflag);
  k_scan2<<<384, 256, 0, stream>>>(dsum, hend, wb, hstart);
  k_scan3ln<<<2304, 192, 0, stream>>>(rbuf, bc, xst, wb, hstart, sidx, ymlm, aflag);
  k_tr_ld<<<1152, 256, 0, stream>>>(ymlm, ymdm);
  k_convlc_bn<<<3072, 256, 0, stream>>>(xconv, wb, lcbuf, stats);
  k_final<<<2304, 128, 0, stream>>>(lcbuf, ymdm, wb, stats, d_out, flag);
}

// Round 17
// 494.536 us; speedup vs baseline: 1.0418x; 1.0328x over previous
//
#include <hip/hip_runtime.h>
#include <hip/hip_bf16.h>

// MambaSpatial: B=32, C_IN=D=96, H=W=48, L=2304, K=2, N=16, R=6.
// R4-R13: segmented scan (32-step, NSEG=72), native-transcendental scan math,
// packed v2f, xv[32] reg prefetch, O(L^2) rank argsort, channel-split x4
// inproj/final, fused gather2, parallel LN stats. R13 = 499.2us.
// R14 FAILED: de-LDS'd scans. R15: B-half staging, neutral.
// R16/R17 FAILED: (192,4) VGPR cap -> spill. R18 (502us): clean.
// R19 (515us): (a) xdbl 22/16 split + (c) bnfin fused saved ~30us, but
//     (b) conv_silu 4-out/thread regressed 28 -> 73us. R20 reverted (b).
// R21: RESUBMIT of R20 unchanged. R20's round ran on a throttled container:
//     profile uniformly 1.73x slow (scan3ln 85.6us @ 805 GB/s vs R18's
//     49.4us @ 1391 GB/s, IDENTICAL counters), acquire 142s, pulls 40s;
//     dur_us 510.7 inconsistent with per-kernel ledger (~470-478 expected).
//     Need a clean measurement before attributing anything.
//     Decision rule: clean <=500 -> keep; clean ~510 healthy -> revert (a).
// conv_silu/sim math deliberately UNCHANGED (feeds argsort; near-tie order).

typedef __hip_bfloat16 bf16;
typedef float v2f __attribute__((ext_vector_type(2)));
typedef float v4f __attribute__((ext_vector_type(4)));
#define SH2(V, a, b) __builtin_shufflevector(V, V, a, b)

__device__ __forceinline__ float b2f(bf16 v) { return __bfloat162float(v); }
__device__ __forceinline__ float ldu(const void* p, int i, bool f32) {
  if (f32) return ((const float*)p)[i];
  return b2f(((const bf16*)p)[i]);
}
__device__ __forceinline__ float rcp_f(float x) { return __builtin_amdgcn_rcpf(x); }

#define LL 2304
#define NSEG 72          // 32-step segments

// ---- wbuf offsets (floats) ----
#define W_INT  0        // in_proj_w transposed [c][d] 9216
#define B_IN   9216
#define W_C2D  9312
#define B_C2D  10176
#define W_LOC  10272
#define B_LOC  11136
#define BN_G   11232
#define BN_B   11328
#define W_XPT  11424    // x_proj_w transposed [d][80]
#define W_DT   19104    // dt_projs_w [k][d][6]
#define B_DT   20256
#define A2OF   20448    // -exp(A_logs)*log2(e) [k][d][16]
#define DSOF   23520
#define LN_G   23712
#define LN_B   23808
#define W_OUTT 23904    // out_proj_w transposed [d][c]
#define B_OUT  33120
#define WBUF_N 33280ul

// ---- workspace layout (float offsets) ----
#define O_WBUF  0ul
#define O_XFEAT 33280ul        // 7,077,888 ; reused: hend ; then ymdm
#define O_XCONV 7111168ul      // 7,077,888
#define O_SIM   14189056ul
#define O_SIDX  14262784ul
#define O_XST   14336512ul     // sorted l-major [b][l][d] ; reused: lcbuf
#define O_XSTD  21414400ul     // sorted d-major [b][d][l] ; reused: hstart
#define O_RBUF  28492288ul     // [b][k][l][8]
#define O_BC    29671936ul     // [b][k][l][32]
#define O_DSUM  34390528ul     // [b][k][d][72] 442,368
#define O_YMLM  34832896ul     // [b][p][96] 7,077,888
#define O_STATS 41910784ul
#define O_AFLG  41910976ul
#define O_SCSH  41911040ul
#define O_FLAG  41911232ul
#define O_END   41911296ul     // ~167.6 MB

// ---------------- dtype detect ----------------
__global__ void k_detect(const void* x, float* flag) {
  int i = threadIdx.x;
  bool bad = false;
  const bf16* xb = (const bf16*)x;
#pragma unroll
  for (int r = 0; r < 4; ++r) {
    float v = b2f(xb[r * 64 + i]);
    if (!(fabsf(v) <= 1e4f)) bad = true;
  }
  bool any = __any(bad);
  if (i == 0) flag[0] = any ? 1.f : 0.f;
}

// ---------------- prep ----------------
__global__ void k_prep(const void* ipw, const void* ipb, const void* c2w, const void* c2b,
                       const void* lw, const void* lb, const void* bng, const void* bnb,
                       const void* xpw, const void* dtw, const void* dtb, const void* alog,
                       const void* dss, const void* ng, const void* nb, const void* opw,
                       const void* opb, float* wb, const float* flag, float* aflag) {
  bool f = flag[0] > 0.5f;
  int i = blockIdx.x * 256 + threadIdx.x;
  if (i < 9216) {
    int r = i / 96, c = i % 96;
    wb[W_INT + c * 96 + r] = ldu(ipw, i, f);
    wb[W_OUTT + c * 96 + r] = ldu(opw, i, f);
  }
  if (i < 96) {
    wb[B_IN + i] = ldu(ipb, i, f); wb[B_C2D + i] = ldu(c2b, i, f); wb[B_LOC + i] = ldu(lb, i, f);
    wb[BN_G + i] = ldu(bng, i, f); wb[BN_B + i] = ldu(bnb, i, f); wb[LN_G + i] = ldu(ng, i, f);
    wb[LN_B + i] = ldu(nb, i, f); wb[B_OUT + i] = ldu(opb, i, f);
  }
  if (i < 864) { wb[W_C2D + i] = ldu(c2w, i, f); wb[W_LOC + i] = ldu(lw, i, f); }
  if (i < 7296) {
    int k = i / 3648, c = (i / 96) % 38, d = i % 96;
    wb[W_XPT + d * 80 + k * 38 + c] = ldu(xpw, i, f);
  }
  if (i < 1152) wb[W_DT + i] = ldu(dtw, i, f);
  if (i < 192) { wb[B_DT + i] = ldu(dtb, i, f); wb[DSOF + i] = ldu(dss, i, f); }
  if (i < 3072) {
    float av = expf(ldu(alog, i, f));
    wb[A2OF + i] = -av * 1.4426950408889634f;
    int n = i % 16;
    if (fabsf(av - (float)(n + 1)) > 1e-3f * (n + 1)) atomicAdd(aflag, 1.f);
  }
}

// ---------------- in_proj (acc-major, d-quarter x4, 128 thr) ----------------
__global__ __launch_bounds__(128, 4)
void k_inproj(const void* __restrict__ x, const float* __restrict__ wb,
              float* __restrict__ xfeat, const float* __restrict__ flag) {
  int b = blockIdx.x / 72;
  int rest = blockIdx.x % 72;
  int q = rest / 18;
  int l = (rest % 18) * 128 + threadIdx.x;
  float acc[24];
#pragma unroll
  for (int j = 0; j < 24; ++j) acc[j] = wb[B_IN + q * 24 + j];
  bool f = flag[0] > 0.5f;
  if (f) {
    const float* xf = (const float*)x;
#pragma unroll 2
    for (int c = 0; c < 96; ++c) {
      float xc = xf[(b * 96 + c) * LL + l];
      const float* wr = wb + W_INT + c * 96 + q * 24;
#pragma unroll
      for (int j = 0; j < 24; ++j) acc[j] += xc * wr[j];
    }
  } else {
    const bf16* xb = (const bf16*)x;
#pragma unroll 2
    for (int c = 0; c < 96; ++c) {
      float xc = b2f(xb[(b * 96 + c) * LL + l]);
      const float* wr = wb + W_INT + c * 96 + q * 24;
#pragma unroll
      for (int j = 0; j < 24; ++j) acc[j] += xc * wr[j];
    }
  }
#pragma unroll
  for (int j = 0; j < 24; ++j) xfeat[(b * 96 + q * 24 + j) * LL + l] = acc[j];
}

// ---------------- depthwise 3x3 + bias + silu (1 output/thread) ----------------
__global__ __launch_bounds__(256, 8)
void k_conv_silu(const float* __restrict__ xfeat, const float* __restrict__ wb,
                 float* __restrict__ xconv) {
  int t = blockIdx.x * 256 + threadIdx.x;
  int l = t % LL; int d = (t / LL) % 96; int b = t / (LL * 96);
  int h = l / 48, w = l % 48;
  const float* wr = wb + W_C2D + d * 9;
  const float* src = xfeat + (b * 96 + d) * LL;
  float acc = wb[B_C2D + d];
#pragma unroll
  for (int ki = 0; ki < 3; ++ki) {
    int hh = h + ki - 1; if (hh < 0 || hh >= 48) continue;
#pragma unroll
    for (int kj = 0; kj < 3; ++kj) {
      int ww = w + kj - 1; if (ww < 0 || ww >= 48) continue;
      acc += src[hh * 48 + ww] * wr[ki * 3 + kj];
    }
  }
  xconv[t] = acc / (1.f + expf(-acc));
}

// ---------------- cosine-sim vs center pixel ----------------
__global__ __launch_bounds__(256, 8)
void k_sim(const float* __restrict__ xconv, float* __restrict__ sim) {
  int b = blockIdx.x / 9;
  int l = (blockIdx.x % 9) * 256 + threadIdx.x;
  const float* base = xconv + (size_t)b * 96 * LL;
  float dot = 0, nrm = 0, cn = 0;
  for (int d = 0; d < 96; ++d) {
    float v = base[d * LL + l];
    float c = base[d * LL + 1176];
    dot += v * c; nrm += v * v; cn += c * c;
  }
  float den = fmaxf(sqrtf(nrm), 1e-12f) * fmaxf(sqrtf(cn), 1e-12f);
  sim[b * LL + l] = dot / den;
}

// ---------------- stable argsort desc via O(L^2) rank-by-count ----------------
__global__ __launch_bounds__(256, 8)
void k_rank(const float* __restrict__ sim, int* __restrict__ sidx) {
  __shared__ unsigned su[LL];
  int b = blockIdx.x / 36;
  int part = blockIdx.x % 36;
  const float* sp = sim + b * LL;
  for (int i = threadIdx.x; i < LL; i += 256) {
    unsigned u = __float_as_uint(sp[i]);
    u = (u >> 31) ? ~u : (u | 0x80000000u);
    su[i] = u;
  }
  __syncthreads();
  int lq = threadIdx.x >> 2;           // 0..63: element within part
  int ch = threadIdx.x & 3;            // 0..3: j-chunk
  int l = part * 64 + lq;
  unsigned ui = su[l];
  int rank = 0;
  const uint4* s4 = (const uint4*)su;
#pragma unroll 4
  for (int it = 0; it < 144; ++it) {
    int m = 4 * it + ch;
    uint4 U = s4[m];
    int j = 4 * m;
    rank += (int)(U.x > ui) + (int)((U.x == ui) & (j + 0 < l));
    rank += (int)(U.y > ui) + (int)((U.y == ui) & (j + 1 < l));
    rank += (int)(U.z > ui) + (int)((U.z == ui) & (j + 2 < l));
    rank += (int)(U.w > ui) + (int)((U.w == ui) & (j + 3 < l));
  }
  rank += __shfl_xor(rank, 1);
  rank += __shfl_xor(rank, 2);
  if (ch == 0) sidx[b * LL + rank] = l;
}

// ---------------- fused gather + transpose: xconv -> xstd (d-major) + xst (l-major) ----------------
__global__ __launch_bounds__(256, 4)
void k_gather2(const float* __restrict__ xconv, const int* __restrict__ sidx,
               float* __restrict__ xstd, float* __restrict__ xst) {
  __shared__ float tile[64 * 97];
  __shared__ int sp[64];
  int b = blockIdx.x / 36;
  int l0 = (blockIdx.x % 36) * 64;
  if (threadIdx.x < 64) sp[threadIdx.x] = sidx[b * LL + l0 + threadIdx.x];
  __syncthreads();
  const float* base = xconv + (size_t)b * 96 * LL;
#pragma unroll
  for (int it = 0; it < 24; ++it) {
    int idx = it * 256 + threadIdx.x;
    int d = idx / 64, j = idx % 64;
    tile[j * 97 + d] = base[d * LL + sp[j]];
  }
  __syncthreads();
#pragma unroll
  for (int it = 0; it < 24; ++it) {
    int idx = it * 256 + threadIdx.x;
    int r = idx / 96, c = idx % 96;
    xst[((size_t)b * LL + l0 + r) * 96 + c] = tile[r * 97 + c];
  }
#pragma unroll
  for (int it = 0; it < 24; ++it) {
    int idx = it * 256 + threadIdx.x;
    int d = idx / 64, j = idx % 64;
    xstd[((size_t)b * 96 + d) * LL + l0 + j] = tile[j * 97 + d];
  }
}

// ---------------- transpose l-major -> d-major (ymlm -> ymdm) ----------------
__global__ __launch_bounds__(256, 4)
void k_tr_ld(const float* __restrict__ in, float* __restrict__ out) {
  __shared__ float tile[64 * 97];
  int b = blockIdx.x / 36;
  int l0 = (blockIdx.x % 36) * 64;
#pragma unroll
  for (int it = 0; it < 24; ++it) {
    int idx = it * 256 + threadIdx.x;
    int r = idx / 96, c = idx % 96;
    tile[r * 97 + c] = in[((size_t)b * LL + l0 + r) * 96 + c];
  }
  __syncthreads();
#pragma unroll
  for (int it = 0; it < 24; ++it) {
    int idx = it * 256 + threadIdx.x;
    int d = idx / 64, j = idx % 64;
    out[((size_t)b * 96 + d) * LL + l0 + j] = tile[j * 97 + d];
  }
}

// ---------------- x_dbl, output-split 22/16, one 2304-block launch ----------------
__global__ __launch_bounds__(128, 4)
void k_xdbl(const float* __restrict__ xstd, const float* __restrict__ wb,
            float* __restrict__ rbuf, float* __restrict__ bc) {
  int half = blockIdx.x / 1152;
  int r2 = blockIdx.x % 1152;
  int kq = r2 / 576;
  int r = r2 % 576;
  int b = r / 18;
  int l = (r % 18) * 128 + threadIdx.x;
  int lout = kq ? (LL - 1 - l) : l;
  if (half == 0) {
    float acc[22];
#pragma unroll
    for (int j = 0; j < 22; ++j) acc[j] = 0.f;
#pragma unroll 2
    for (int c = 0; c < 96; ++c) {
      float xc = xstd[((size_t)b * 96 + c) * LL + l];
      const float* wr = wb + W_XPT + c * 80 + kq * 38;   // uniform -> s_load
#pragma unroll
      for (int j = 0; j < 22; ++j) acc[j] += xc * wr[j];
    }
    float4* r4 = (float4*)(rbuf + ((size_t)(b * 2 + kq) * LL + lout) * 8);
    r4[0] = make_float4(acc[0], acc[1], acc[2], acc[3]);
    r4[1] = make_float4(acc[4], acc[5], 0.f, 0.f);
    float4* b4 = (float4*)(bc + ((size_t)(b * 2 + kq) * LL + lout) * 32);
#pragma unroll
    for (int i = 0; i < 4; ++i)
      b4[i] = make_float4(acc[6 + 4 * i], acc[7 + 4 * i], acc[8 + 4 * i], acc[9 + 4 * i]);
  } else {
    float acc[16];
#pragma unroll
    for (int j = 0; j < 16; ++j) acc[j] = 0.f;
#pragma unroll 2
    for (int c = 0; c < 96; ++c) {
      float xc = xstd[((size_t)b * 96 + c) * LL + l];
      const float* wr = wb + W_XPT + c * 80 + kq * 38 + 22;
#pragma unroll
      for (int j = 0; j < 16; ++j) acc[j] += xc * wr[j];
    }
    float4* b4 = (float4*)(bc + ((size_t)(b * 2 + kq) * LL + lout) * 32);
#pragma unroll
    for (int i = 0; i < 4; ++i)
      b4[4 + i] = make_float4(acc[4 * i], acc[4 * i + 1], acc[4 * i + 2], acc[4 * i + 3]);
  }
}

// ---------------- scan pass 1: 32-step segments, LDS-staged B-half + rr ----------------
__global__ __launch_bounds__(192, 3)
void k_scan1(const float* __restrict__ rbuf, const float* __restrict__ bc,
             const float* __restrict__ xst, const float* __restrict__ wb,
             float* __restrict__ dsum, float* __restrict__ hend,
             const float* __restrict__ aflag) {
  __shared__ float sbc[2][512];
  __shared__ float srr[2][256];
  int sub = threadIdx.x / 96;
  int tid = threadIdx.x - sub * 96;
  int unit = blockIdx.x * 2 + sub;             // b*144 + k*72 + s
  int s = unit % 72; int k = (unit / 72) % 2; int b = unit / 144;
  int lbase = (b * 2 + k) * LL + s * 32;
  long long lk0 = k ? (LL - 1 - s * 32) : (s * 32);
  long long stp = k ? -96 : 96;
  const float* xp = xst + (size_t)b * LL * 96 + lk0 * 96 + tid;
  float xv[32];
#pragma unroll
  for (int t = 0; t < 32; ++t) xv[t] = xp[t * stp];
  {
    const float4* bsrc = (const float4*)(bc + (size_t)lbase * 32);
    float4* bdst = (float4*)sbc[sub];
    for (int i = tid; i < 128; i += 96) {
      int l = i >> 2, c = i & 3;
      bdst[i] = bsrc[l * 8 + c];     // B-half: first 4 of 8 chunks per l
    }
    const float4* rsrc = (const float4*)(rbuf + (size_t)lbase * 8);
    float4* rdst = (float4*)srr[sub];
    if (tid < 64) rdst[tid] = rsrc[tid];
  }
  __syncthreads();
  int d = tid;
  float wd[6];
#pragma unroll
  for (int j = 0; j < 6; ++j) wd[j] = wb[W_DT + (k * 96 + d) * 6 + j];
  float bd = wb[B_DT + k * 96 + d];
  float ds = 0.f;
  v2f h2[8];
#pragma unroll
  for (int j = 0; j < 8; ++j) h2[j] = (v2f){0.f, 0.f};
  bool fast = (aflag[0] == 0.f);
  if (fast) {
    const v4f* bq4 = (const v4f*)sbc[sub];
    const v4f* rq4 = (const v4f*)srr[sub];
#pragma unroll
    for (int t = 0; t < 32; ++t) {
      v4f r0 = rq4[t * 2], r1 = rq4[t * 2 + 1];
      float a = bd + r0.x * wd[0] + r0.y * wd[1] + r0.z * wd[2]
                   + r0.w * wd[3] + r1.x * wd[4] + r1.y * wd[5];
      float ea = __expf(a);
      float p1 = rcp_f(1.f + ea);
      float dtv = (a > 20.f) ? a : -0.69314718055994531f * __log2f(p1);
      ds += dtv;
      float dtx = dtv * xv[t];
      v2f dt2 = {dtx, dtx};
      float p2s = p1 * p1;
      v2f P1 = {p1, p2s};
      v2f P2 = P1 * (v2f){p2s, p2s};        // p3,p4
      float p4s = P2.y;
      v2f P3 = P1 * (v2f){p4s, p4s};        // p5,p6
      v2f P4 = P2 * (v2f){p4s, p4s};        // p7,p8
      float p8s = P4.y;
      v2f P5 = P1 * (v2f){p8s, p8s};        // p9,p10
      v2f P6 = P2 * (v2f){p8s, p8s};        // p11,p12
      v2f P7 = P3 * (v2f){p8s, p8s};        // p13,p14
      v2f P8 = P4 * (v2f){p8s, p8s};        // p15,p16
      v4f B0 = bq4[t * 4 + 0], B1 = bq4[t * 4 + 1];
      v4f B2 = bq4[t * 4 + 2], B3 = bq4[t * 4 + 3];
      h2[0] = P1 * h2[0] + dt2 * SH2(B0, 0, 1);
      h2[1] = P2 * h2[1] + dt2 * SH2(B0, 2, 3);
      h2[2] = P3 * h2[2] + dt2 * SH2(B1, 0, 1);
      h2[3] = P4 * h2[3] + dt2 * SH2(B1, 2, 3);
      h2[4] = P5 * h2[4] + dt2 * SH2(B2, 0, 1);
      h2[5] = P6 * h2[5] + dt2 * SH2(B2, 2, 3);
      h2[6] = P7 * h2[6] + dt2 * SH2(B3, 0, 1);
      h2[7] = P8 * h2[7] + dt2 * SH2(B3, 2, 3);
    }
  } else {
    float a2[16], hh[16];
#pragma unroll
    for (int n = 0; n < 16; ++n) { a2[n] = wb[A2OF + (k * 96 + d) * 16 + n]; hh[n] = 0.f; }
#pragma unroll 4
    for (int t = 0; t < 32; ++t) {
      const float* rr = &srr[sub][t * 8];
      float a = bd + rr[0] * wd[0] + rr[1] * wd[1] + rr[2] * wd[2]
                   + rr[3] * wd[3] + rr[4] * wd[4] + rr[5] * wd[5];
      float dtv = (a > 20.f) ? a : log1pf(expf(a));
      ds += dtv;
      float dtx = dtv * xv[t];
      const float* bcl = &sbc[sub][t * 16];
#pragma unroll
      for (int n = 0; n < 16; ++n) hh[n] = exp2f(dtv * a2[n]) * hh[n] + dtx * bcl[n];
    }
#pragma unroll
    for (int j = 0; j < 8; ++j) h2[j] = (v2f){hh[2 * j], hh[2 * j + 1]};
  }
  dsum[((b * 2 + k) * 96 + d) * NSEG + s] = ds;
  float4* ho = (float4*)(hend + (((size_t)(b * 2 + k) * NSEG + s) * 96 + d) * 16);
  ho[0] = make_float4(h2[0].x, h2[0].y, h2[1].x, h2[1].y);
  ho[1] = make_float4(h2[2].x, h2[2].y, h2[3].x, h2[3].y);
  ho[2] = make_float4(h2[4].x, h2[4].y, h2[5].x, h2[5].y);
  ho[3] = make_float4(h2[6].x, h2[6].y, h2[7].x, h2[7].y);
}

// ---------------- scan pass 2: stitch 72 segments ----------------
__global__ __launch_bounds__(256, 4)
void k_scan2(const float* __restrict__ dsum, const float* __restrict__ hend,
             const float* __restrict__ wb, float* __restrict__ hstart) {
  int t = blockIdx.x * 256 + threadIdx.x;
  int n = t % 16; int d = (t / 16) % 96; int k = (t / 1536) % 2; int b = t / 3072;
  float a2 = wb[A2OF + (k * 96 + d) * 16 + n];
  float h = 0.f;
  int rowd = ((b * 2 + k) * 96 + d) * NSEG;
#pragma unroll 8
  for (int s = 0; s < NSEG; ++s) {
    size_t idx = (((size_t)(b * 2 + k) * NSEG + s) * 96 + d) * 16 + n;
    hstart[idx] = h;
    h = exp2f(a2 * dsum[rowd + s]) * h + hend[idx];
  }
}

// ---------------- scan3 + combine + LN (32-row tiles, staged) ----------------
__global__ __launch_bounds__(192, 3)
void k_scan3ln(const float* __restrict__ rbuf, const float* __restrict__ bc,
               const float* __restrict__ xst, const float* __restrict__ wb,
               const float* __restrict__ hstart, const int* __restrict__ sidx,
               float* __restrict__ ymlm, const float* __restrict__ aflag) {
  __shared__ float yA[32 * 97];
  __shared__ float yB[32 * 97];
  __shared__ float sbc[2][1024];
  __shared__ float srr[2][256];
  __shared__ float smu[32], srs[32];
  int b = blockIdx.x / NSEG;
  int u = blockIdx.x % NSEG;
  int t = threadIdx.x;
  int sub = t / 96;                      // sub==k
  int d = t - sub * 96;
  int k = sub;
  int seg = sub ? (NSEG - 1 - u) : u;
  int lbase = (b * 2 + k) * LL + seg * 32;
  long long lk0 = k ? (LL - 1 - seg * 32) : (seg * 32);
  long long stp = k ? -96 : 96;
  const float* xp = xst + (size_t)b * LL * 96 + lk0 * 96 + d;
  float xv[32];
#pragma unroll
  for (int i = 0; i < 32; ++i) xv[i] = xp[i * stp];
  {
    const float4* bsrc = (const float4*)(bc + (size_t)lbase * 32);
    float4* bdst = (float4*)sbc[sub];
    for (int i = d; i < 256; i += 96) bdst[i] = bsrc[i];
    const float4* rsrc = (const float4*)(rbuf + (size_t)lbase * 8);
    float4* rdst = (float4*)srr[sub];
    if (d < 64) rdst[d] = rsrc[d];
  }
  __syncthreads();
  {
    float* yacc = sub ? yB : yA;
    float wd[6];
#pragma unroll
    for (int j = 0; j < 6; ++j) wd[j] = wb[W_DT + (k * 96 + d) * 6 + j];
    float bd = wb[B_DT + k * 96 + d];
    float Dv = wb[DSOF + k * 96 + d];
    const float* hi = hstart + (((size_t)(b * 2 + k) * NSEG + seg) * 96 + d) * 16;
    bool fast = (aflag[0] == 0.f);
    if (fast) {
      const v4f* hi4 = (const v4f*)hi;
      v4f H0 = hi4[0], H1 = hi4[1], H2 = hi4[2], H3 = hi4[3];
      v2f h2[8];
      h2[0] = SH2(H0, 0, 1); h2[1] = SH2(H0, 2, 3);
      h2[2] = SH2(H1, 0, 1); h2[3] = SH2(H1, 2, 3);
      h2[4] = SH2(H2, 0, 1); h2[5] = SH2(H2, 2, 3);
      h2[6] = SH2(H3, 0, 1); h2[7] = SH2(H3, 2, 3);
      const v4f* bq4 = (const v4f*)sbc[sub];
      const v4f* rq4 = (const v4f*)srr[sub];
#pragma unroll
      for (int i = 0; i < 32; ++i) {
        v4f r0 = rq4[i * 2], r1 = rq4[i * 2 + 1];
        float a = bd + r0.x * wd[0] + r0.y * wd[1] + r0.z * wd[2]
                     + r0.w * wd[3] + r1.x * wd[4] + r1.y * wd[5];
        float ea = __expf(a);
        float p1 = rcp_f(1.f + ea);
        float dtv = (a > 20.f) ? a : -0.69314718055994531f * __log2f(p1);
        float dtx = dtv * xv[i];
        v2f dt2 = {dtx, dtx};
        float p2s = p1 * p1;
        v2f P1 = {p1, p2s};
        v2f P2 = P1 * (v2f){p2s, p2s};
        float p4s = P2.y;
        v2f P3 = P1 * (v2f){p4s, p4s};
        v2f P4 = P2 * (v2f){p4s, p4s};
        float p8s = P4.y;
        v2f P5 = P1 * (v2f){p8s, p8s};
        v2f P6 = P2 * (v2f){p8s, p8s};
        v2f P7 = P3 * (v2f){p8s, p8s};
        v2f P8 = P4 * (v2f){p8s, p8s};
        v4f B0 = bq4[i * 8 + 0], B1 = bq4[i * 8 + 1];
        v4f B2 = bq4[i * 8 + 2], B3 = bq4[i * 8 + 3];
        v4f C0 = bq4[i * 8 + 4], C1 = bq4[i * 8 + 5];
        v4f C2 = bq4[i * 8 + 6], C3 = bq4[i * 8 + 7];
        v2f y2;
        h2[0] = P1 * h2[0] + dt2 * SH2(B0, 0, 1); y2  = h2[0] * SH2(C0, 0, 1);
        h2[1] = P2 * h2[1] + dt2 * SH2(B0, 2, 3); y2 += h2[1] * SH2(C0, 2, 3);
        h2[2] = P3 * h2[2] + dt2 * SH2(B1, 0, 1); y2 += h2[2] * SH2(C1, 0, 1);
        h2[3] = P4 * h2[3] + dt2 * SH2(B1, 2, 3); y2 += h2[3] * SH2(C1, 2, 3);
        h2[4] = P5 * h2[4] + dt2 * SH2(B2, 0, 1); y2 += h2[4] * SH2(C2, 0, 1);
        h2[5] = P6 * h2[5] + dt2 * SH2(B2, 2, 3); y2 += h2[5] * SH2(C2, 2, 3);
        h2[6] = P7 * h2[6] + dt2 * SH2(B3, 0, 1); y2 += h2[6] * SH2(C3, 0, 1);
        h2[7] = P8 * h2[7] + dt2 * SH2(B3, 2, 3); y2 += h2[7] * SH2(C3, 2, 3);
        int qloc = k ? (31 - i) : i;
        yacc[qloc * 97 + d] = y2.x + y2.y + Dv * xv[i];
      }
    } else {
      float a2[16], hh[16];
#pragma unroll
      for (int n = 0; n < 16; ++n) { a2[n] = wb[A2OF + (k * 96 + d) * 16 + n]; hh[n] = hi[n]; }
#pragma unroll 4
      for (int i = 0; i < 32; ++i) {
        const float* rr = &srr[sub][i * 8];
        float a = bd + rr[0] * wd[0] + rr[1] * wd[1] + rr[2] * wd[2]
                     + rr[3] * wd[3] + rr[4] * wd[4] + rr[5] * wd[5];
        float dtv = (a > 20.f) ? a : log1pf(expf(a));
        float dtx = dtv * xv[i];
        const float* bcl = &sbc[sub][i * 32];
        float y = 0.f;
#pragma unroll
        for (int n = 0; n < 16; ++n) {
          hh[n] = exp2f(dtv * a2[n]) * hh[n] + dtx * bcl[n];
          y += hh[n] * bcl[16 + n];
        }
        int qloc = k ? (31 - i) : i;
        yacc[qloc * 97 + d] = y + Dv * xv[i];
      }
    }
  }
  __syncthreads();
  // parallel LN stats, conflict-free mapping: r=t&31, g=t>>5 (bit-identical sums)
  {
    float* p1 = &srr[0][0];          // 192 floats
    float* p2 = &srr[0][0] + 192;    // 192 floats (srr holds 512 total)
    int r = t & 31, c0 = (t >> 5) * 16;
    float s = 0, ss = 0;
#pragma unroll
    for (int j = 0; j < 16; ++j) {
      float v = yA[r * 97 + c0 + j] + yB[r * 97 + c0 + j];
      s += v; ss += v * v;
    }
    p1[t] = s; p2[t] = ss;
  }
  __syncthreads();
  if (t < 32) {
    const float* p1 = &srr[0][0];
    const float* p2 = &srr[0][0] + 192;
    float s = 0, ss = 0;
#pragma unroll
    for (int g = 0; g < 6; ++g) { s += p1[g * 32 + t]; ss += p2[g * 32 + t]; }
    float mu = s * (1.f / 96.f);
    float var = ss * (1.f / 96.f) - mu * mu;
    smu[t] = mu;
    srs[t] = rsqrtf(var + 1e-5f);
  }
  __syncthreads();
  {
    int r = t & 31, c0 = (t >> 5) * 16;
    int q = u * 32 + r;
    int p = sidx[b * LL + q];
    float mu = smu[r], rs = srs[r];
    float tmp[16];
#pragma unroll
    for (int j = 0; j < 16; ++j) {
      int dd = c0 + j;
      tmp[j] = (yA[r * 97 + dd] + yB[r * 97 + dd] - mu) * rs * wb[LN_G + dd] + wb[LN_B + dd];
    }
    float4* o4 = (float4*)(ymlm + ((size_t)b * LL + p) * 96 + c0);
    o4[0] = make_float4(tmp[0], tmp[1], tmp[2], tmp[3]);
    o4[1] = make_float4(tmp[4], tmp[5], tmp[6], tmp[7]);
    o4[2] = make_float4(tmp[8], tmp[9], tmp[10], tmp[11]);
    o4[3] = make_float4(tmp[12], tmp[13], tmp[14], tmp[15]);
  }
}

// ---------------- local conv + bias + BN stats (fused) ----------------
__global__ __launch_bounds__(256, 8)
void k_convlc_bn(const float* __restrict__ xconv, const float* __restrict__ wb,
                 float* __restrict__ lcbuf, float* __restrict__ stats) {
  int bd = blockIdx.x;
  int b = bd / 96, d = bd % 96;
  const float* src = xconv + (size_t)(b * 96 + d) * LL;
  const float* wr = wb + W_LOC + d * 9;
  float bias = wb[B_LOC + d];
  float s1 = 0, s2 = 0;
  for (int l = threadIdx.x; l < LL; l += 256) {
    int h = l / 48, w = l % 48;
    float acc = bias;
#pragma unroll
    for (int ki = 0; ki < 3; ++ki) {
      int hh = h + ki - 1; if (hh < 0 || hh >= 48) continue;
#pragma unroll
      for (int kj = 0; kj < 3; ++kj) {
        int ww = w + kj - 1; if (ww < 0 || ww >= 48) continue;
        acc += src[hh * 48 + ww] * wr[ki * 3 + kj];
      }
    }
    lcbuf[(size_t)(b * 96 + d) * LL + l] = acc;
    s1 += acc; s2 += acc * acc;
  }
  __shared__ float r1[256], r2[256];
  r1[threadIdx.x] = s1; r2[threadIdx.x] = s2; __syncthreads();
  for (int o = 128; o > 0; o >>= 1) {
    if (threadIdx.x < o) { r1[threadIdx.x] += r1[threadIdx.x + o]; r2[threadIdx.x] += r2[threadIdx.x + o]; }
    __syncthreads();
  }
  if (threadIdx.x == 0) { atomicAdd(&stats[d], r1[0]); atomicAdd(&stats[96 + d], r2[0]); }
}

// ---------------- final (acc-major, c-quarter x4, 128 thr; bnfin fused) ----------------
__global__ __launch_bounds__(128, 4)
void k_final(const float* __restrict__ lcbuf, const float* __restrict__ ymdm,
             const float* __restrict__ wb, const float* __restrict__ stats,
             void* __restrict__ out, const float* __restrict__ flag) {
  int b = blockIdx.x / 72;
  int rest = blockIdx.x % 72;
  int q = rest / 18;
  int l = (rest % 18) * 128 + threadIdx.x;
  float acc[24];
#pragma unroll
  for (int j = 0; j < 24; ++j) acc[j] = wb[B_OUT + q * 24 + j];
#pragma unroll 2
  for (int d = 0; d < 96; ++d) {
    float mean = stats[d] * (1.f / 73728.f);
    float var = stats[96 + d] * (1.f / 73728.f) - mean * mean;
    float sc = wb[BN_G + d] * rsqrtf(var + 1e-5f);
    float sh = wb[BN_B + d] - mean * sc;
    float lc = lcbuf[((size_t)b * 96 + d) * LL + l] * sc + sh;
    float vd = lc * rcp_f(1.f + __expf(-lc)) + ymdm[((size_t)b * 96 + d) * LL + l];
    const float* wr = wb + W_OUTT + d * 96 + q * 24;   // uniform -> s_load
#pragma unroll
    for (int j = 0; j < 24; ++j) acc[j] += vd * wr[j];
  }
  bool f = flag[0] > 0.5f;
  if (f) {
    float* of = (float*)out;
#pragma unroll
    for (int j = 0; j < 24; ++j) of[(b * 96 + q * 24 + j) * LL + l] = acc[j];
  } else {
    bf16* ob = (bf16*)out;
#pragma unroll
    for (int j = 0; j < 24; ++j) ob[(b * 96 + q * 24 + j) * LL + l] = __float2bfloat16(acc[j]);
  }
}

extern "C" void kernel_launch(void* const* d_in, const int* in_sizes, int n_in,
                              void* d_out, int out_size, void* d_ws, size_t ws_size,
                              hipStream_t stream) {
  if (ws_size < O_END * sizeof(float)) return;
  float* ws = (float*)d_ws;
  float* wb    = ws + O_WBUF;
  float* xfeat = ws + O_XFEAT;
  float* xconv = ws + O_XCONV;
  float* sim   = ws + O_SIM;
  int*   sidx  = (int*)(ws + O_SIDX);
  float* xst   = ws + O_XST;
  float* xstd  = ws + O_XSTD;
  float* rbuf  = ws + O_RBUF;
  float* bc    = ws + O_BC;
  float* dsum  = ws + O_DSUM;
  float* ymlm  = ws + O_YMLM;
  float* stats = ws + O_STATS;
  float* aflag = ws + O_AFLG;
  float* flag  = ws + O_FLAG;
  float* hend   = xfeat;   // xfeat dead after conv_silu
  float* hstart = xstd;    // xstd dead after xdbl
  float* ymdm   = xfeat;   // hend dead after scan2 read / scan3ln
  float* lcbuf  = xst;     // xst dead after scan3ln

  hipMemsetAsync(stats, 0, 256 * sizeof(float), stream);   // stats + aflag
  k_detect<<<1, 64, 0, stream>>>(d_in[0], flag);
  k_prep<<<36, 256, 0, stream>>>(
      d_in[1], d_in[2], d_in[5], d_in[6], d_in[7], d_in[8], d_in[9], d_in[10],
      d_in[11], d_in[12], d_in[13], d_in[14], d_in[15], d_in[16], d_in[17], d_in[18],
      d_in[19], wb, flag, aflag);
  k_inproj<<<2304, 128, 0, stream>>>(d_in[0], wb, xfeat, flag);
  k_conv_silu<<<27648, 256, 0, stream>>>(xfeat, wb, xconv);
  k_sim<<<288, 256, 0, stream>>>(xconv, sim);
  k_rank<<<1152, 256, 0, stream>>>(sim, sidx);
  k_gather2<<<1152, 256, 0, stream>>>(xconv, sidx, xstd, xst);
  k_xdbl<<<2304, 128, 0, stream>>>(xstd, wb, rbuf, bc);
  k_scan1<<<2304, 192, 0, stream>>>(rbuf, bc, xst, wb, dsum, hend, aflag);
  k_scan2<<<384, 256, 0, stream>>>(dsum, hend, wb, hstart);
  k_scan3ln<<<2304, 192, 0, stream>>>(rbuf, bc, xst, wb, hstart, sidx, ymlm, aflag);
  k_tr_ld<<<1152, 256, 0, stream>>>(ymlm, ymdm);
  k_convlc_bn<<<3072, 256, 0, stream>>>(xconv, wb, lcbuf, stats);
  k_final<<<2304, 128, 0, stream>>>(lcbuf, ymdm, wb, stats, d_out, flag);
}